// Round 4
// baseline (503.368 us; speedup 1.0000x reference)
//
#include <hip/hip_runtime.h>
#include <hip/hip_bf16.h>
#include <stdint.h>

using u16 = unsigned short;
typedef float floatx4 __attribute__((ext_vector_type(4)));
typedef __bf16 bfv8 __attribute__((ext_vector_type(8)));

#define AS1 __attribute__((address_space(1)))
#define AS3 __attribute__((address_space(3)))

__device__ __forceinline__ u16 f2bf_bits(float f) {
    __hip_bfloat16 h = __float2bfloat16(f);
    u16 u;
    __builtin_memcpy(&u, &h, 2);
    return u;
}
__device__ __forceinline__ float bf_bits2f(u16 u) {
    __hip_bfloat16 h;
    __builtin_memcpy(&h, &u, 2);
    return __bfloat162float(h);
}
__device__ __forceinline__ void gload_lds16(const void* g, void* l) {
    __builtin_amdgcn_global_load_lds((AS1 void*)(uintptr_t)g, (AS3 void*)l, 16, 0, 0);
}

// ---- BK=64 tile staging (dbuf), XOR-swizzled chunks (R6-proven) ----
__device__ __forceinline__ void stage64(const u16* __restrict__ Abase, long lda, const long* arow,
                                        const u16* __restrict__ Bb, long ldb, int k0, int tid,
                                        u16* Ad, u16* Bd) {
    #pragma unroll
    for (int j = 0; j < 4; ++j) {
        const int q   = j * 256 + tid;
        const int row = q >> 3;
        const int cg  = (q & 7) ^ (row & 7);
        gload_lds16(Abase + arow[j] * lda + k0 + cg * 8, Ad + q * 8);
        gload_lds16(Bb + (long)row * ldb + k0 + cg * 8, Bd + q * 8);
    }
}
__device__ __forceinline__ void compute64(const u16* Ab, const u16* Bb, int wy, int wx,
                                          int quad, int mrow, floatx4 acc[4][4]) {
    #pragma unroll
    for (int kk = 0; kk < 2; ++kk) {
        bfv8 af[4], bf[4];
        #pragma unroll
        for (int mi = 0; mi < 4; mi++) {
            const int r = wy * 64 + mi * 16 + mrow;
            const int slot = (kk * 4 + quad) ^ (r & 7);
            af[mi] = *(const bfv8*)&Ab[r * 64 + slot * 8];
        }
        #pragma unroll
        for (int ni = 0; ni < 4; ni++) {
            const int r = wx * 64 + ni * 16 + mrow;
            const int slot = (kk * 4 + quad) ^ (r & 7);
            bf[ni] = *(const bfv8*)&Bb[r * 64 + slot * 8];
        }
        #pragma unroll
        for (int mi = 0; mi < 4; mi++)
            #pragma unroll
            for (int ni = 0; ni < 4; ni++)
                acc[mi][ni] = __builtin_amdgcn_mfma_f32_16x16x32_bf16(af[mi], bf[ni], acc[mi][ni], 0, 0, 0);
    }
}

// ---------------- cast fp32 -> bf16 (+ fused bias pack in tail blocks) ----------------
__global__ void cast_bf16_kernel(const float* __restrict__ in, u16* __restrict__ out, int n4,
                                 const float* __restrict__ bq, const float* __restrict__ bk,
                                 const float* __restrict__ bv, float* __restrict__ pb) {
    if (blockIdx.x >= 2048) {
        int j = (blockIdx.x - 2048) * 256 + threadIdx.x;  // 0..12287
        const float* s = j < 4096 ? bq : (j < 8192 ? bk : bv);
        pb[j] = s[j & 4095];
        return;
    }
    int i = blockIdx.x * blockDim.x + threadIdx.x;
    if (i >= n4) return;
    float4 v = ((const float4*)in)[i];
    ushort4 o;
    o.x = f2bf_bits(v.x); o.y = f2bf_bits(v.y); o.z = f2bf_bits(v.z); o.w = f2bf_bits(v.w);
    ((ushort4*)out)[i] = o;
}

// ---------------- transpose+cast fp32 [z][R][C] -> bf16 [z][C][R] ----------------
__global__ void transpose_cast_kernel(const float* __restrict__ src, u16* __restrict__ dst,
                                      int R, int C, long sSrc, long sDst) {
    __shared__ float tile[32][33];
    const float* s = src + (long)blockIdx.z * sSrc;
    u16* d = dst + (long)blockIdx.z * sDst;
    int c0 = blockIdx.x * 32, r0 = blockIdx.y * 32;
    int tx = threadIdx.x, ty = threadIdx.y;
    #pragma unroll
    for (int i = 0; i < 4; i++)
        tile[ty + 8*i][tx] = s[(long)(r0 + ty + 8*i) * C + c0 + tx];
    __syncthreads();
    #pragma unroll
    for (int i = 0; i < 4; i++)
        d[(long)(c0 + ty + 8*i) * R + r0 + tx] = f2bf_bits(tile[tx][ty + 8*i]);
}

// ---------------- merged transpose+cast for wq,wk,wv,wo (512x512 each, z=0..31) ----------------
__global__ void transpose_cast4_kernel(const float* __restrict__ w0, const float* __restrict__ w1p,
                                       const float* __restrict__ w2p, const float* __restrict__ w3p,
                                       u16* __restrict__ dst) {
    __shared__ float tile[32][33];
    int z = blockIdx.z;
    const float* s = (z < 8 ? w0 : z < 16 ? w1p : z < 24 ? w2p : w3p) + (long)(z & 7) * 262144;
    u16* d = dst + (long)z * 262144;
    int c0 = blockIdx.x * 32, r0 = blockIdx.y * 32;
    int tx = threadIdx.x, ty = threadIdx.y;
    #pragma unroll
    for (int i = 0; i < 4; i++)
        tile[ty + 8*i][tx] = s[(long)(r0 + ty + 8*i) * 512 + c0 + tx];
    __syncthreads();
    #pragma unroll
    for (int i = 0; i < 4; i++)
        d[(long)(c0 + ty + 8*i) * 512 + r0 + tx] = f2bf_bits(tile[tx][ty + 8*i]);
}

// ---------------- router ----------------
__global__ __launch_bounds__(512)
void router_kernel(const float* __restrict__ x, const float* __restrict__ gw,
                   const float* __restrict__ gb, float* __restrict__ rw,
                   float* __restrict__ logits_out) {
    int row = blockIdx.x;
    int w = threadIdx.x >> 6;
    int lane = threadIdx.x & 63;
    const float* xr = x + (long)row * 512;
    float sum = 0.f;
    #pragma unroll
    for (int i = 0; i < 8; i++) {
        int d = lane + 64 * i;
        sum += xr[d] * gw[d * 8 + w];
    }
    #pragma unroll
    for (int o = 32; o; o >>= 1) sum += __shfl_down(sum, o, 64);
    __shared__ float lg[8];
    if (lane == 0) lg[w] = sum + gb[w];
    __syncthreads();
    if (threadIdx.x == 0) {
        float l[8];
        #pragma unroll
        for (int e = 0; e < 8; e++) l[e] = lg[e];
        int i1 = 0;
        for (int e = 1; e < 8; e++) if (l[e] > l[i1]) i1 = e;
        int i2 = -1;
        for (int e = 0; e < 8; e++) { if (e == i1) continue; if (i2 < 0 || l[e] > l[i2]) i2 = e; }
        for (int e = 0; e < 8; e++) {
            float v = (e == i1 || e == i2) ? (l[e] > 0.f ? l[e] : 0.f) : 0.f;
            float r = 0.f, mem = v;
            #pragma unroll
            for (int lvl = 0; lvl < 4; lvl++) {
                float thr = 4.0f / (float)(1 << lvl);
                if (mem >= thr) { r += thr; mem -= thr; }
            }
            rw[(long)row * 8 + e] = r;
            logits_out[(long)row * 8 + e] = l[e];
        }
    }
}

// ---------------- build packed row space: per b, experts packed back-to-back ----------------
__global__ __launch_bounds__(256)
void build_lists_kernel(const float* __restrict__ rw, int* __restrict__ prix,
                        int* __restrict__ act, int* __restrict__ smap,
                        int* __restrict__ tmap, int* __restrict__ tt, int* __restrict__ pt) {
    int b = blockIdx.x;
    int t = threadIdx.x, wv = t >> 6, lane = t & 63;
    __shared__ int wsum[4];
    __shared__ int base_sh;
    if (t == 0) base_sh = 0;
    __syncthreads();
    for (int e = 0; e < 8; e++) {
        int r0 = b * 1024 + t * 4;
        int f[4], c = 0;
        #pragma unroll
        for (int i = 0; i < 4; i++) {
            f[i] = (rw[(long)(r0 + i) * 8 + e] != 0.f) ? 1 : 0;
            c += f[i];
        }
        int incl = c;
        #pragma unroll
        for (int o = 1; o < 64; o <<= 1) {
            int n = __shfl_up(incl, o, 64);
            if (lane >= o) incl += n;
        }
        if (lane == 63) wsum[wv] = incl;
        __syncthreads();
        int woff = 0;
        #pragma unroll
        for (int k = 0; k < 4; k++) if (k < wv) woff += wsum[k];
        int tot = wsum[0] + wsum[1] + wsum[2] + wsum[3];
        int excl = incl - c + woff;
        int base = base_sh;
        int slot = excl;
        #pragma unroll
        for (int i = 0; i < 4; i++) {
            int r = r0 + i;
            if (f[i]) {
                int ps = base + slot;
                prix[b * 3072 + ps] = r;
                act[b * 3072 + ps] = 1;
                smap[(long)r * 8 + e] = ps;
                slot++;
            } else {
                smap[(long)r * 8 + e] = -1;
            }
        }
        int pad = (tot + 127) & ~127;
        for (int s = tot + t; s < pad; s += 256) {
            prix[b * 3072 + base + s] = b * 1024;
            act[b * 3072 + base + s] = 0;
        }
        for (int k = t; k < (pad >> 7); k += 256)
            tmap[b * 32 + (base >> 7) + k] = e;
        __syncthreads();
        if (t == 0) base_sh = base + pad;
        __syncthreads();
    }
    if (t == 0) {
        tt[b] = base_sh >> 7;
        pt[b] = base_sh;
    }
}

// ---------------- dense GEMM (K / V projections): C = A @ Bt^T + bias ----------------
template<bool TRANSC>
__global__ __launch_bounds__(256)
void gemm_dense_kernel(const u16* __restrict__ A,
                       const u16* __restrict__ B, long sB,
                       u16* __restrict__ C, long sC,
                       const float* __restrict__ bias, int K) {
    __shared__ __align__(16) u16 As[2][128 * 64];
    __shared__ __align__(16) u16 Bs[2][128 * 64];
    const int z = blockIdx.z;
    const u16* Bb = B + (long)z * sB + (long)blockIdx.x * 128 * 512;

    const int tid = threadIdx.x;
    const int w = tid >> 6, lane = tid & 63;
    const int wy = w >> 1, wx = w & 1;
    const int quad = lane >> 4, mrow = lane & 15;

    long arow[4];
    #pragma unroll
    for (int j = 0; j < 4; ++j) arow[j] = (long)blockIdx.y * 128 + ((j * 256 + tid) >> 3);

    floatx4 acc[4][4];
    #pragma unroll
    for (int i = 0; i < 4; i++)
        #pragma unroll
        for (int j = 0; j < 4; j++)
            acc[i][j] = floatx4{0.f, 0.f, 0.f, 0.f};

    const int nk = K >> 6;
    stage64(A, 512, arow, Bb, 512, 0, tid, As[0], Bs[0]);
    for (int it = 0; it < nk; ++it) {
        const int cur = it & 1;
        __syncthreads();
        if (it + 1 < nk)
            stage64(A, 512, arow, Bb, 512, (it + 1) << 6, tid, As[1 - cur], Bs[1 - cur]);
        compute64(As[cur], Bs[cur], wy, wx, quad, mrow, acc);
    }

    const float* biasb = bias + (long)z * 512 + blockIdx.x * 128;
    if constexpr (TRANSC) {
        u16* Cb = C + (long)z * sC;
        #pragma unroll
        for (int ni = 0; ni < 4; ni++) {
            const int colt = wx * 64 + ni * 16 + mrow;
            const int n = blockIdx.x * 128 + colt;
            float bv = biasb[colt];
            #pragma unroll
            for (int mi = 0; mi < 4; mi++) {
                #pragma unroll
                for (int r = 0; r < 4; r++) {
                    const int m = blockIdx.y * 128 + wy * 64 + mi * 16 + quad * 4 + r;
                    float v = acc[mi][ni][r] + bv;
                    long addr = ((long)(((m >> 10) << 2) + (n >> 7)) * 128 + (n & 127)) * 1024 + (m & 1023);
                    Cb[addr] = f2bf_bits(v);
                }
            }
        }
    } else {
        u16* Cb = C + (long)z * sC + (long)blockIdx.y * 128 * 512 + blockIdx.x * 128;
        #pragma unroll
        for (int ni = 0; ni < 4; ni++) {
            const int col = wx * 64 + ni * 16 + mrow;
            float bv = biasb[col];
            #pragma unroll
            for (int mi = 0; mi < 4; mi++) {
                #pragma unroll
                for (int r = 0; r < 4; r++) {
                    const int row = wy * 64 + mi * 16 + quad * 4 + r;
                    Cb[(long)row * 512 + col] = f2bf_bits(acc[mi][ni][r] + bv);
                }
            }
        }
    }
}

// ---------------- fused attention, software-pipelined 64-key steps ----------------
// grid x=24 (packed tiles), y=16 (b*4+h). OC block-exclusively aliases QP (read in prologue).
// Per step s: [B1; issue V(s) loads; write K(s) LDS (waits vmcnt(4)); B2;
//              QK(s); exp; issue K(s+1) loads; write V(s)+P(s) (waits vmcnt(4)); B3; PV(s)]
// No vmcnt(0) drains in steady state; all global loads fly under a full compute phase.
__global__ __launch_bounds__(256, 2)
void attn_fused_kernel(const u16* __restrict__ QP, const u16* __restrict__ Km,
                       const u16* __restrict__ VT, u16* __restrict__ OC,
                       const int* __restrict__ tmap, const int* __restrict__ tt, float alpha) {
    const int tile = blockIdx.x;
    const int bh = blockIdx.y;
    const int b = bh >> 2, h = bh & 3;
    if (tile >= tt[b]) return;
    const int e = tmap[b * 32 + tile];

    __shared__ __align__(16) u16 Kb[64 * 128];    // K step tile [64 k][128 d], swizzled 16B chunks
    __shared__ __align__(16) u16 Vb[128 * 64];    // V step tile [128 d][64 k]
    __shared__ __align__(16) u16 Pb[128 * 64];    // P step tile [128 q][64 k]; Q staging in prologue
    __shared__ float rs_sh[2][128];

    const int tid = threadIdx.x;
    const int w = tid >> 6, lane = tid & 63;
    const int wy = w >> 1, wx = w & 1;
    const int quad = lane >> 4, mrow = lane & 15;

    const u16* Qbase = QP + ((long)b * 3072 + tile * 128) * 512 + h * 128;
    const u16* Kbase = Km + ((long)e * 4096 + b * 1024) * 512 + h * 128;
    const u16* Vbase = VT + ((long)e * 16 + bh) * 131072;

    // per-thread staging coordinates
    const int krow[4] = { (0*256+tid)>>4, (1*256+tid)>>4, (2*256+tid)>>4, (3*256+tid)>>4 };
    const int kc  [4] = { (0*256+tid)&15, (1*256+tid)&15, (2*256+tid)&15, (3*256+tid)&15 };
    const int vrow[4] = { (0*256+tid)>>3, (1*256+tid)>>3, (2*256+tid)>>3, (3*256+tid)>>3 };
    const int vc  [4] = { (0*256+tid)&7,  (1*256+tid)&7,  (2*256+tid)&7,  (3*256+tid)&7  };

    float4 kreg[4], vreg[4];
    // prefetch K(0)
    #pragma unroll
    for (int j = 0; j < 4; ++j)
        kreg[j] = *(const float4*)(Kbase + (long)krow[j] * 512 + kc[j] * 8);

    // ---- prologue: Q -> registers (two 64-d halves staged through Pb) ----
    bfv8 qf[4][4];
    #pragma unroll
    for (int dh = 0; dh < 2; ++dh) {
        #pragma unroll
        for (int j = 0; j < 4; ++j) {
            const int q0 = j * 256 + tid;
            const int row = q0 >> 3, c = q0 & 7, cg = c ^ (row & 7);
            gload_lds16(Qbase + (long)row * 512 + dh * 64 + cg * 8, Pb + q0 * 8);
        }
        __syncthreads();
        #pragma unroll
        for (int dkl = 0; dkl < 2; ++dkl)
            #pragma unroll
            for (int ni = 0; ni < 4; ++ni) {
                const int q = wx * 64 + ni * 16 + mrow;
                const int c = dkl * 4 + quad;
                qf[dh * 2 + dkl][ni] = *(const bfv8*)&Pb[q * 64 + (c ^ (q & 7)) * 8];
            }
        __syncthreads();
    }

    floatx4 acc_o[4][4];
    float rsum[4];
    #pragma unroll
    for (int i = 0; i < 4; i++) {
        rsum[i] = 0.f;
        #pragma unroll
        for (int j = 0; j < 4; j++) acc_o[i][j] = floatx4{0.f, 0.f, 0.f, 0.f};
    }

    for (int s = 0; s < 16; ++s) {
        __syncthreads();                     // B1: prev PV done with Vb/Pb, prev QK done with Kb
        // issue V(s) loads (land under QK phase)
        #pragma unroll
        for (int j = 0; j < 4; ++j)
            vreg[j] = *(const float4*)(Vbase + (long)vrow[j] * 1024 + s * 64 + vc[j] * 8);
        // write K(s) into Kb, swizzled (waits only for kreg: counted vmcnt)
        #pragma unroll
        for (int j = 0; j < 4; ++j) {
            const int cs = (kc[j] & 8) | ((kc[j] & 7) ^ (krow[j] & 7));
            *(float4*)(Kb + krow[j] * 128 + cs * 8) = kreg[j];
        }
        __syncthreads();                     // B2: Kb ready (LDS-only drain)

        // QK: S^T[key 64][q 128], wave = (wy key-half 32, wx q-half 64)
        floatx4 acc_s[2][4];
        #pragma unroll
        for (int i = 0; i < 2; i++)
            #pragma unroll
            for (int j = 0; j < 4; j++) acc_s[i][j] = floatx4{0.f, 0.f, 0.f, 0.f};
        #pragma unroll
        for (int dk = 0; dk < 4; ++dk) {
            bfv8 af[2];
            #pragma unroll
            for (int mi = 0; mi < 2; ++mi) {
                const int row = wy * 32 + mi * 16 + mrow;
                const int c = dk * 4 + quad;
                const int cs = (c & 8) | ((c & 7) ^ (row & 7));
                af[mi] = *(const bfv8*)&Kb[row * 128 + cs * 8];
            }
            #pragma unroll
            for (int mi = 0; mi < 2; ++mi)
                #pragma unroll
                for (int ni = 0; ni < 4; ++ni)
                    acc_s[mi][ni] = __builtin_amdgcn_mfma_f32_16x16x32_bf16(af[mi], qf[dk][ni], acc_s[mi][ni], 0, 0, 0);
        }
        // exp + per-lane row sums
        #pragma unroll
        for (int mi = 0; mi < 2; ++mi)
            #pragma unroll
            for (int ni = 0; ni < 4; ++ni)
                #pragma unroll
                for (int r = 0; r < 4; ++r) {
                    float p = __expf(acc_s[mi][ni][r] * alpha);
                    acc_s[mi][ni][r] = p;
                    rsum[ni] += p;
                }
        // prefetch K(s+1) (lands under V/P write + PV phase)
        const int sn = (s < 15) ? s + 1 : 15;
        #pragma unroll
        for (int j = 0; j < 4; ++j)
            kreg[j] = *(const float4*)(Kbase + (long)(sn * 64 + krow[j]) * 512 + kc[j] * 8);
        // write V(s) (waits only for vreg: counted vmcnt) + P(s)
        #pragma unroll
        for (int j = 0; j < 4; ++j)
            *(float4*)(Vb + vrow[j] * 64 + (vc[j] ^ (vrow[j] & 7)) * 8) = vreg[j];
        #pragma unroll
        for (int mi = 0; mi < 2; ++mi)
            #pragma unroll
            for (int ni = 0; ni < 4; ++ni) {
                const int q = wx * 64 + ni * 16 + mrow;
                const int cc = wy * 4 + mi * 2 + (quad >> 1);
                u16* pr = Pb + q * 64 + ((cc ^ (q & 7)) * 8) + (quad & 1) * 4;
                uint2 pk;
                pk.x = (uint32_t)f2bf_bits(acc_s[mi][ni][0]) | ((uint32_t)f2bf_bits(acc_s[mi][ni][1]) << 16);
                pk.y = (uint32_t)f2bf_bits(acc_s[mi][ni][2]) | ((uint32_t)f2bf_bits(acc_s[mi][ni][3]) << 16);
                *(uint2*)pr = pk;
            }
        __syncthreads();                     // B3: Vb + Pb ready (LDS-only drain)

        // PV: O^T[d 128][q 128] += V^T[d][64k] P^T[64k][q], wave = (wy d-half, wx q-half)
        #pragma unroll
        for (int kw = 0; kw < 2; ++kw) {
            bfv8 vf[4], pf[4];
            #pragma unroll
            for (int mi = 0; mi < 4; ++mi) {
                const int row = wy * 64 + mi * 16 + mrow;
                const int c = kw * 4 + quad;
                vf[mi] = *(const bfv8*)&Vb[row * 64 + (c ^ (row & 7)) * 8];
            }
            #pragma unroll
            for (int ni = 0; ni < 4; ++ni) {
                const int q = wx * 64 + ni * 16 + mrow;
                const int c = kw * 4 + quad;
                pf[ni] = *(const bfv8*)&Pb[q * 64 + (c ^ (q & 7)) * 8];
            }
            #pragma unroll
            for (int mi = 0; mi < 4; ++mi)
                #pragma unroll
                for (int ni = 0; ni < 4; ++ni)
                    acc_o[mi][ni] = __builtin_amdgcn_mfma_f32_16x16x32_bf16(vf[mi], pf[ni], acc_o[mi][ni], 0, 0, 0);
        }
    }

    // row sums: reduce over quad lanes, then across wy waves via LDS
    #pragma unroll
    for (int ni = 0; ni < 4; ni++) {
        float v = rsum[ni];
        v += __shfl_xor(v, 16, 64);
        v += __shfl_xor(v, 32, 64);
        if (quad == 0) rs_sh[wy][wx * 64 + ni * 16 + mrow] = v;
    }
    __syncthreads();
    u16* Cb = OC + ((long)b * 3072 + tile * 128) * 512 + h * 128;
    #pragma unroll
    for (int ni = 0; ni < 4; ni++) {
        const int q = wx * 64 + ni * 16 + mrow;
        const float inv = 1.f / (rs_sh[0][q] + rs_sh[1][q]);
        #pragma unroll
        for (int mi = 0; mi < 4; mi++) {
            ushort4 st;
            st.x = f2bf_bits(acc_o[mi][ni][0] * inv);
            st.y = f2bf_bits(acc_o[mi][ni][1] * inv);
            st.z = f2bf_bits(acc_o[mi][ni][2] * inv);
            st.w = f2bf_bits(acc_o[mi][ni][3] * inv);
            *(ushort4*)(Cb + (long)q * 512 + wy * 64 + mi * 16 + quad * 4) = st;
        }
    }
}

// ---------------- packed GEMM (Qp / Wo / FFN1 / FFN2): per-tile expert weights ----------------
// grid x = N/128, y = 96 (b = y/24, tile = y%24); GATHER: A rows via prix
template<bool RELU, bool GATHER>
__global__ __launch_bounds__(256)
void gemm_packed_kernel(const u16* __restrict__ A, int lda,
                        const u16* __restrict__ B, int ldb, long sBe,
                        u16* __restrict__ C, int ldc,
                        const float* __restrict__ bias, long sBiasE,
                        const int* __restrict__ tmap, const int* __restrict__ tt, int K,
                        const int* __restrict__ prix) {
    const int b = blockIdx.y / 24, tile = blockIdx.y % 24;
    if (tile >= tt[b]) return;
    const int e = tmap[b * 32 + tile];
    __shared__ __align__(16) u16 As[2][128 * 64];
    __shared__ __align__(16) u16 Bs[2][128 * 64];
    const long rbase = (long)b * 3072 + tile * 128;
    const u16* Ab = GATHER ? A : A + rbase * lda;
    const u16* Bb = B + (long)e * sBe + (long)blockIdx.x * 128 * ldb;

    const int tid = threadIdx.x;
    const int w = tid >> 6, lane = tid & 63;
    const int wy = w >> 1, wx = w & 1;
    const int quad = lane >> 4, mrow = lane & 15;

    long arow[4];
    #pragma unroll
    for (int j = 0; j < 4; ++j) {
        const int lr = (j * 256 + tid) >> 3;
        arow[j] = GATHER ? (long)prix[b * 3072 + tile * 128 + lr] : (long)lr;
    }

    floatx4 acc[4][4];
    #pragma unroll
    for (int i = 0; i < 4; i++)
        #pragma unroll
        for (int j = 0; j < 4; j++)
            acc[i][j] = floatx4{0.f, 0.f, 0.f, 0.f};

    const int nk = K >> 6;
    stage64(Ab, lda, arow, Bb, ldb, 0, tid, As[0], Bs[0]);
    for (int it = 0; it < nk; ++it) {
        const int cur = it & 1;
        __syncthreads();
        if (it + 1 < nk)
            stage64(Ab, lda, arow, Bb, ldb, (it + 1) << 6, tid, As[1 - cur], Bs[1 - cur]);
        compute64(As[cur], Bs[cur], wy, wx, quad, mrow, acc);
    }

    u16* Cb = C + rbase * ldc + (long)blockIdx.x * 128;
    const float* biasb = bias + (long)e * sBiasE + blockIdx.x * 128;
    #pragma unroll
    for (int ni = 0; ni < 4; ni++) {
        const int col = wx * 64 + ni * 16 + mrow;
        float bv = biasb[col];
        #pragma unroll
        for (int mi = 0; mi < 4; mi++) {
            #pragma unroll
            for (int r = 0; r < 4; r++) {
                const int row = wy * 64 + mi * 16 + quad * 4 + r;
                float v = acc[mi][ni][r] + bv;
                if (RELU) v = fmaxf(v, 0.f);
                Cb[(long)row * ldc + col] = f2bf_bits(v);
            }
        }
    }
}

// ---------------- LN1 on packed rows ----------------
__global__ __launch_bounds__(128)
void ln1_kernel(const float* __restrict__ x, const u16* __restrict__ tc,
                const int* __restrict__ prix, const int* __restrict__ act,
                const int* __restrict__ tmap, const int* __restrict__ pt,
                const float* __restrict__ s_all, const float* __restrict__ b_all,
                u16* __restrict__ hb) {
    int blk = blockIdx.x;
    int b = blk / 3072, pslot = blk % 3072;
    if (pslot >= pt[b]) return;
    long row = (long)b * 3072 + pslot;
    int tid = threadIdx.x, w = tid >> 6, lane = tid & 63;
    if (!act[row]) {
        *(ushort4*)(hb + row * 512 + tid * 4) = make_ushort4(0, 0, 0, 0);
        return;
    }
    int r = prix[row];
    int e = tmap[b * 32 + (pslot >> 7)];
    float4 xv = *(const float4*)(x + (long)r * 512 + tid * 4);
    ushort4 tu = *(const ushort4*)(tc + row * 512 + tid * 4);
    float v[4] = {xv.x + bf_bits2f(tu.x), xv.y + bf_bits2f(tu.y),
                  xv.z + bf_bits2f(tu.z), xv.w + bf_bits2f(tu.w)};
    float sum = v[0] + v[1] + v[2] + v[3];
    #pragma unroll
    for (int o = 32; o; o >>= 1) sum += __shfl_down(sum, o, 64);
    __shared__ float sh[4];
    if (lane == 0) sh[w] = sum;
    __syncthreads();
    float mu = (sh[0] + sh[1]) * (1.f / 512.f);
    float sq = 0.f;
    #pragma unroll
    for (int j = 0; j < 4; j++) { float d = v[j] - mu; sq += d * d; }
    #pragma unroll
    for (int o = 32; o; o >>= 1) sq += __shfl_down(sq, o, 64);
    if (lane == 0) sh[2 + w] = sq;
    __syncthreads();
    float inv = 1.f / sqrtf((sh[2] + sh[3]) * (1.f / 512.f) + 1e-5f);
    float4 sv = *(const float4*)(s_all + e * 512 + tid * 4);
    float4 bv = *(const float4*)(b_all + e * 512 + tid * 4);
    ushort4 ub;
    ub.x = f2bf_bits((v[0] - mu) * inv * sv.x + bv.x);
    ub.y = f2bf_bits((v[1] - mu) * inv * sv.y + bv.y);
    ub.z = f2bf_bits((v[2] - mu) * inv * sv.z + bv.z);
    ub.w = f2bf_bits((v[3] - mu) * inv * sv.w + bv.w);
    *(ushort4*)(hb + row * 512 + tid * 4) = ub;
}

// ---------------- LN2 + weighted accumulate over all 8 experts ----------------
__global__ __launch_bounds__(128)
void ln2acc_kernel(const u16* __restrict__ hb, const u16* __restrict__ t2,
                   const float* __restrict__ s_all, const float* __restrict__ b_all,
                   const float* __restrict__ rw, const int* __restrict__ smap,
                   float* __restrict__ out) {
    long r = blockIdx.x;
    int b = (int)(r >> 10);
    int tid = threadIdx.x, w = tid >> 6, lane = tid & 63;
    __shared__ float sh[4];
    float4 acc = make_float4(0.f, 0.f, 0.f, 0.f);
    for (int e = 0; e < 8; e++) {
        int ps = smap[r * 8 + e];
        if (ps >= 0) {   // block-uniform
            float wgt = rw[r * 8 + e];
            long row = (long)b * 3072 + ps;
            ushort4 hu = *(const ushort4*)(hb + row * 512 + tid * 4);
            ushort4 fu = *(const ushort4*)(t2 + row * 512 + tid * 4);
            float v[4] = {bf_bits2f(hu.x) + bf_bits2f(fu.x), bf_bits2f(hu.y) + bf_bits2f(fu.y),
                          bf_bits2f(hu.z) + bf_bits2f(fu.z), bf_bits2f(hu.w) + bf_bits2f(fu.w)};
            float sum = v[0] + v[1] + v[2] + v[3];
            #pragma unroll
            for (int o = 32; o; o >>= 1) sum += __shfl_down(sum, o, 64);
            if (lane == 0) sh[w] = sum;
            __syncthreads();
            float mu = (sh[0] + sh[1]) * (1.f / 512.f);
            float sq = 0.f;
            #pragma unroll
            for (int j = 0; j < 4; j++) { float d = v[j] - mu; sq += d * d; }
            #pragma unroll
            for (int o = 32; o; o >>= 1) sq += __shfl_down(sq, o, 64);
            if (lane == 0) sh[2 + w] = sq;
            __syncthreads();
            float inv = 1.f / sqrtf((sh[2] + sh[3]) * (1.f / 512.f) + 1e-5f);
            float4 sv = *(const float4*)(s_all + e * 512 + tid * 4);
            float4 bv = *(const float4*)(b_all + e * 512 + tid * 4);
            acc.x += wgt * ((v[0] - mu) * inv * sv.x + bv.x);
            acc.y += wgt * ((v[1] - mu) * inv * sv.y + bv.y);
            acc.z += wgt * ((v[2] - mu) * inv * sv.z + bv.z);
            acc.w += wgt * ((v[3] - mu) * inv * sv.w + bv.w);
            __syncthreads();
        }
    }
    *(float4*)(out + r * 512 + tid * 4) = acc;
}

// ---------------- workspace layout (bytes), ws_size = 256 MiB ----------------
static const size_t WB_B   = 0;           // 48 MiB: wq,wk,wv,wo (8x262144 each), w1 (8x1048576), w2 (8x1048576)
static const size_t RW_B   = 50331648;    // f32 [4096][8]
static const size_t PB_B   = 50462720;    // f32 [3][8][512]
static const size_t TT_B   = 50511872;    // i32[4] tiles per b
static const size_t PT_B   = 50511888;    // i32[4] packed rows per b
static const size_t TMAP_B = 50511904;    // i32 [4][32]
static const size_t PRIX_B = 50512416;    // i32 [4][3072]
static const size_t ACT_B  = 50561568;    // i32 [4][3072]
static const size_t SMAP_B = 50610720;    // i32 [4096][8]
static const size_t XB_B   = 50741792;    // bf16 [4096][512]
static const size_t Q8_B   = 54936096;    // bf16 packed Q [4][3072][512] (12.6 MiB)
static const size_t K8_B   = 88490528;    // bf16 [8][4096][512] (32 MiB)
static const size_t VT_B   = 122044960;   // bf16 [8][16][128][1024] (32 MiB)
static const size_t S_B    = 155599392;   // scratch region (FFN mid), 96 MiB
static const size_t OC_B   = Q8_B;        // fused attn out: block-exclusive alias of QP
static const size_t TC_B   = K8_B;        // bf16 [4][3072][512] — K dead after attn
static const size_t HB_B   = Q8_B;        // LN1 out — OC dead after Wo
static const size_t MID_B  = S_B;         // bf16 [4][3072][2048] (50 MB)
static const size_t T2_B   = VT_B;        // bf16 [4][3072][512] — VT dead after attn

extern "C" void kernel_launch(void* const* d_in, const int* in_sizes, int n_in,
                              void* d_out, int out_size, void* d_ws, size_t ws_size,
                              hipStream_t stream) {
    const float* x      = (const float*)d_in[0];
    const float* gate_w = (const float*)d_in[1];
    const float* gate_b = (const float*)d_in[2];
    const float* ln1_s  = (const float*)d_in[3];
    const float* ln1_b  = (const float*)d_in[4];
    const float* ln2_s  = (const float*)d_in[5];
    const float* ln2_b  = (const float*)d_in[6];
    const float* wq = (const float*)d_in[7];
    const float* wk = (const float*)d_in[8];
    const float* wv = (const float*)d_in[9];
    const float* wo = (const float*)d_in[10];
    const float* bo = (const float*)d_in[14];
    const float* w1 = (const float*)d_in[15];
    const float* b1 = (const float*)d_in[16];
    const float* w2 = (const float*)d_in[17];
    const float* b2 = (const float*)d_in[18];
    float* out = (float*)d_out;

    char* ws = (char*)d_ws;
    u16*   WB   = (u16*)(ws + WB_B);
    float* RW   = (float*)(ws + RW_B);
    float* PB   = (float*)(ws + PB_B);
    int*   TT   = (int*)(ws + TT_B);
    int*   PT   = (int*)(ws + PT_B);
    int*   TMAP = (int*)(ws + TMAP_B);
    int*   PRIX = (int*)(ws + PRIX_B);
    int*   ACT  = (int*)(ws + ACT_B);
    int*   SMAP = (int*)(ws + SMAP_B);
    u16*   XB   = (u16*)(ws + XB_B);
    u16*   QP   = (u16*)(ws + Q8_B);
    u16*   K8   = (u16*)(ws + K8_B);
    u16*   VT8  = (u16*)(ws + VT_B);
    u16*   OC   = (u16*)(ws + OC_B);
    u16*   TC   = (u16*)(ws + TC_B);
    u16*   HB   = (u16*)(ws + HB_B);
    u16*   MID  = (u16*)(ws + MID_B);
    u16*   T2   = (u16*)(ws + T2_B);

    // ---- setup ----
    cast_bf16_kernel<<<dim3(2096), 256, 0, stream>>>(x, XB, 4096 * 512 / 4,
                                                     (const float*)d_in[11], (const float*)d_in[12],
                                                     (const float*)d_in[13], PB);
    transpose_cast4_kernel<<<dim3(16,16,32), dim3(32,8), 0, stream>>>(wq, wk, wv, wo, WB);
    transpose_cast_kernel<<<dim3(64,16,8), dim3(32,8), 0, stream>>>(w1, WB + 8388608,  512,  2048, 1048576, 1048576);
    transpose_cast_kernel<<<dim3(16,64,8), dim3(32,8), 0, stream>>>(w2, WB + 16777216, 2048, 512,  1048576, 1048576);
    router_kernel<<<4096, 512, 0, stream>>>(x, gate_w, gate_b, RW, out + 2097152);
    build_lists_kernel<<<4, 256, 0, stream>>>(RW, PRIX, ACT, SMAP, TMAP, TT, PT);

    const float isq = 0.08838834764831845f;  // 1/sqrt(128)

    // ---- K for all 8 experts (dense: all rows are attention keys) ----
    gemm_dense_kernel<false><<<dim3(4,32,8), 256, 0, stream>>>(
        XB, WB + 2097152, 262144, K8, 2097152, PB + 4096, 512);
    // ---- V for all 8 experts, direct-transposed into VT ----
    gemm_dense_kernel<true><<<dim3(4,32,8), 256, 0, stream>>>(
        XB, WB + 4194304, 262144, VT8, 2097152, PB + 8192, 512);
    // ---- Q only for packed (routed) rows, gathered from x ----
    gemm_packed_kernel<false, true><<<dim3(4,96), 256, 0, stream>>>(
        XB, 512, WB, 512, 262144, QP, 512, PB, 512, TMAP, TT, 512, PRIX);

    // ---- fused attention (pipelined, 16 x 64-key steps) ----
    attn_fused_kernel<<<dim3(24, 16), 256, 0, stream>>>(QP, K8, VT8, OC, TMAP, TT, isq);

    // ---- Wo ----
    gemm_packed_kernel<false, false><<<dim3(4,96), 256, 0, stream>>>(
        OC, 512, WB + 6291456, 512, 262144, TC, 512, bo, 512, TMAP, TT, 512, nullptr);
    // ---- LN1 ----
    ln1_kernel<<<12288, 128, 0, stream>>>(x, TC, PRIX, ACT, TMAP, PT, ln1_s, ln1_b, HB);
    // ---- FFN1 ----
    gemm_packed_kernel<true, false><<<dim3(16,96), 256, 0, stream>>>(
        HB, 512, WB + 8388608, 512, 1048576, MID, 2048, b1, 2048, TMAP, TT, 512, nullptr);
    // ---- FFN2 ----
    gemm_packed_kernel<false, false><<<dim3(4,96), 256, 0, stream>>>(
        MID, 2048, WB + 16777216, 2048, 1048576, T2, 512, b2, 512, TMAP, TT, 2048, nullptr);
    // ---- LN2 + routing-weighted accumulate ----
    ln2acc_kernel<<<4096, 128, 0, stream>>>(HB, T2, ln2_s, ln2_b, RW, SMAP, out);
}

// Round 6
// 459.720 us; speedup vs baseline: 1.0949x; 1.0949x over previous
//
#include <hip/hip_runtime.h>
#include <hip/hip_bf16.h>
#include <stdint.h>

using u16 = unsigned short;
typedef float floatx4 __attribute__((ext_vector_type(4)));
typedef __bf16 bfv8 __attribute__((ext_vector_type(8)));

#define AS1 __attribute__((address_space(1)))
#define AS3 __attribute__((address_space(3)))

__device__ __forceinline__ u16 f2bf_bits(float f) {
    __hip_bfloat16 h = __float2bfloat16(f);
    u16 u;
    __builtin_memcpy(&u, &h, 2);
    return u;
}
__device__ __forceinline__ float bf_bits2f(u16 u) {
    __hip_bfloat16 h;
    __builtin_memcpy(&h, &u, 2);
    return __bfloat162float(h);
}
__device__ __forceinline__ void gload_lds16(const void* g, void* l) {
    __builtin_amdgcn_global_load_lds((AS1 void*)(uintptr_t)g, (AS3 void*)l, 16, 0, 0);
}

// ---- BK=64 tile staging (dbuf), XOR-swizzled chunks (R6-proven) ----
__device__ __forceinline__ void stage64(const u16* __restrict__ Abase, long lda, const long* arow,
                                        const u16* __restrict__ Bb, long ldb, int k0, int tid,
                                        u16* Ad, u16* Bd) {
    #pragma unroll
    for (int j = 0; j < 4; ++j) {
        const int q   = j * 256 + tid;
        const int row = q >> 3;
        const int cg  = (q & 7) ^ (row & 7);
        gload_lds16(Abase + arow[j] * lda + k0 + cg * 8, Ad + q * 8);
        gload_lds16(Bb + (long)row * ldb + k0 + cg * 8, Bd + q * 8);
    }
}
// stage a single 128x64 chunk (contiguous rows)
__device__ __forceinline__ void stage_one(const u16* __restrict__ base, long ld, int tid, u16* dst) {
    #pragma unroll
    for (int j = 0; j < 4; ++j) {
        const int q   = j * 256 + tid;
        const int row = q >> 3;
        const int cg  = (q & 7) ^ (row & 7);
        gload_lds16(base + (long)row * ld + cg * 8, dst + q * 8);
    }
}
__device__ __forceinline__ void compute64(const u16* Ab, const u16* Bb, int wy, int wx,
                                          int quad, int mrow, floatx4 acc[4][4]) {
    #pragma unroll
    for (int kk = 0; kk < 2; ++kk) {
        bfv8 af[4], bf[4];
        #pragma unroll
        for (int mi = 0; mi < 4; mi++) {
            const int r = wy * 64 + mi * 16 + mrow;
            const int slot = (kk * 4 + quad) ^ (r & 7);
            af[mi] = *(const bfv8*)&Ab[r * 64 + slot * 8];
        }
        #pragma unroll
        for (int ni = 0; ni < 4; ni++) {
            const int r = wx * 64 + ni * 16 + mrow;
            const int slot = (kk * 4 + quad) ^ (r & 7);
            bf[ni] = *(const bfv8*)&Bb[r * 64 + slot * 8];
        }
        #pragma unroll
        for (int mi = 0; mi < 4; mi++)
            #pragma unroll
            for (int ni = 0; ni < 4; ni++)
                acc[mi][ni] = __builtin_amdgcn_mfma_f32_16x16x32_bf16(af[mi], bf[ni], acc[mi][ni], 0, 0, 0);
    }
}
// A from LDS (K-tile rows=keys), B from registers (Q fragments)
__device__ __forceinline__ void computeQK(const u16* Kb, const bfv8 qf[2][4], int wy,
                                          int quad, int mrow, floatx4 acc[4][4]) {
    #pragma unroll
    for (int kk = 0; kk < 2; ++kk) {
        bfv8 af[4];
        #pragma unroll
        for (int mi = 0; mi < 4; mi++) {
            const int r = wy * 64 + mi * 16 + mrow;
            const int slot = (kk * 4 + quad) ^ (r & 7);
            af[mi] = *(const bfv8*)&Kb[r * 64 + slot * 8];
        }
        #pragma unroll
        for (int mi = 0; mi < 4; mi++)
            #pragma unroll
            for (int ni = 0; ni < 4; ni++)
                acc[mi][ni] = __builtin_amdgcn_mfma_f32_16x16x32_bf16(af[mi], qf[kk][ni], acc[mi][ni], 0, 0, 0);
    }
}

// ---------------- cast fp32 -> bf16 (+ fused bias pack in tail blocks) ----------------
__global__ void cast_bf16_kernel(const float* __restrict__ in, u16* __restrict__ out, int n4,
                                 const float* __restrict__ bq, const float* __restrict__ bk,
                                 const float* __restrict__ bv, float* __restrict__ pb) {
    if (blockIdx.x >= 2048) {
        int j = (blockIdx.x - 2048) * 256 + threadIdx.x;  // 0..12287
        const float* s = j < 4096 ? bq : (j < 8192 ? bk : bv);
        pb[j] = s[j & 4095];
        return;
    }
    int i = blockIdx.x * blockDim.x + threadIdx.x;
    if (i >= n4) return;
    float4 v = ((const float4*)in)[i];
    ushort4 o;
    o.x = f2bf_bits(v.x); o.y = f2bf_bits(v.y); o.z = f2bf_bits(v.z); o.w = f2bf_bits(v.w);
    ((ushort4*)out)[i] = o;
}

// ---------------- transpose+cast fp32 [z][R][C] -> bf16 [z][C][R] ----------------
__global__ void transpose_cast_kernel(const float* __restrict__ src, u16* __restrict__ dst,
                                      int R, int C, long sSrc, long sDst) {
    __shared__ float tile[32][33];
    const float* s = src + (long)blockIdx.z * sSrc;
    u16* d = dst + (long)blockIdx.z * sDst;
    int c0 = blockIdx.x * 32, r0 = blockIdx.y * 32;
    int tx = threadIdx.x, ty = threadIdx.y;
    #pragma unroll
    for (int i = 0; i < 4; i++)
        tile[ty + 8*i][tx] = s[(long)(r0 + ty + 8*i) * C + c0 + tx];
    __syncthreads();
    #pragma unroll
    for (int i = 0; i < 4; i++)
        d[(long)(c0 + ty + 8*i) * R + r0 + tx] = f2bf_bits(tile[tx][ty + 8*i]);
}

// ---------------- merged transpose+cast for wq,wk,wv,wo (512x512 each, z=0..31) ----------------
__global__ void transpose_cast4_kernel(const float* __restrict__ w0, const float* __restrict__ w1p,
                                       const float* __restrict__ w2p, const float* __restrict__ w3p,
                                       u16* __restrict__ dst) {
    __shared__ float tile[32][33];
    int z = blockIdx.z;
    const float* s = (z < 8 ? w0 : z < 16 ? w1p : z < 24 ? w2p : w3p) + (long)(z & 7) * 262144;
    u16* d = dst + (long)z * 262144;
    int c0 = blockIdx.x * 32, r0 = blockIdx.y * 32;
    int tx = threadIdx.x, ty = threadIdx.y;
    #pragma unroll
    for (int i = 0; i < 4; i++)
        tile[ty + 8*i][tx] = s[(long)(r0 + ty + 8*i) * 512 + c0 + tx];
    __syncthreads();
    #pragma unroll
    for (int i = 0; i < 4; i++)
        d[(long)(c0 + ty + 8*i) * 512 + r0 + tx] = f2bf_bits(tile[tx][ty + 8*i]);
}

// ---------------- router ----------------
__global__ __launch_bounds__(512)
void router_kernel(const float* __restrict__ x, const float* __restrict__ gw,
                   const float* __restrict__ gb, float* __restrict__ rw,
                   float* __restrict__ logits_out) {
    int row = blockIdx.x;
    int w = threadIdx.x >> 6;
    int lane = threadIdx.x & 63;
    const float* xr = x + (long)row * 512;
    float sum = 0.f;
    #pragma unroll
    for (int i = 0; i < 8; i++) {
        int d = lane + 64 * i;
        sum += xr[d] * gw[d * 8 + w];
    }
    #pragma unroll
    for (int o = 32; o; o >>= 1) sum += __shfl_down(sum, o, 64);
    __shared__ float lg[8];
    if (lane == 0) lg[w] = sum + gb[w];
    __syncthreads();
    if (threadIdx.x == 0) {
        float l[8];
        #pragma unroll
        for (int e = 0; e < 8; e++) l[e] = lg[e];
        int i1 = 0;
        for (int e = 1; e < 8; e++) if (l[e] > l[i1]) i1 = e;
        int i2 = -1;
        for (int e = 0; e < 8; e++) { if (e == i1) continue; if (i2 < 0 || l[e] > l[i2]) i2 = e; }
        for (int e = 0; e < 8; e++) {
            float v = (e == i1 || e == i2) ? (l[e] > 0.f ? l[e] : 0.f) : 0.f;
            float r = 0.f, mem = v;
            #pragma unroll
            for (int lvl = 0; lvl < 4; lvl++) {
                float thr = 4.0f / (float)(1 << lvl);
                if (mem >= thr) { r += thr; mem -= thr; }
            }
            rw[(long)row * 8 + e] = r;
            logits_out[(long)row * 8 + e] = l[e];
        }
    }
}

// ---------------- build packed row space: per b, experts packed back-to-back ----------------
__global__ __launch_bounds__(256)
void build_lists_kernel(const float* __restrict__ rw, int* __restrict__ prix,
                        int* __restrict__ act, int* __restrict__ smap,
                        int* __restrict__ tmap, int* __restrict__ tt, int* __restrict__ pt) {
    int b = blockIdx.x;
    int t = threadIdx.x, wv = t >> 6, lane = t & 63;
    __shared__ int wsum[4];
    __shared__ int base_sh;
    if (t == 0) base_sh = 0;
    __syncthreads();
    for (int e = 0; e < 8; e++) {
        int r0 = b * 1024 + t * 4;
        int f[4], c = 0;
        #pragma unroll
        for (int i = 0; i < 4; i++) {
            f[i] = (rw[(long)(r0 + i) * 8 + e] != 0.f) ? 1 : 0;
            c += f[i];
        }
        int incl = c;
        #pragma unroll
        for (int o = 1; o < 64; o <<= 1) {
            int n = __shfl_up(incl, o, 64);
            if (lane >= o) incl += n;
        }
        if (lane == 63) wsum[wv] = incl;
        __syncthreads();
        int woff = 0;
        #pragma unroll
        for (int k = 0; k < 4; k++) if (k < wv) woff += wsum[k];
        int tot = wsum[0] + wsum[1] + wsum[2] + wsum[3];
        int excl = incl - c + woff;
        int base = base_sh;
        int slot = excl;
        #pragma unroll
        for (int i = 0; i < 4; i++) {
            int r = r0 + i;
            if (f[i]) {
                int ps = base + slot;
                prix[b * 3072 + ps] = r;
                act[b * 3072 + ps] = 1;
                smap[(long)r * 8 + e] = ps;
                slot++;
            } else {
                smap[(long)r * 8 + e] = -1;
            }
        }
        int pad = (tot + 127) & ~127;
        for (int s = tot + t; s < pad; s += 256) {
            prix[b * 3072 + base + s] = b * 1024;
            act[b * 3072 + base + s] = 0;
        }
        for (int k = t; k < (pad >> 7); k += 256)
            tmap[b * 32 + (base >> 7) + k] = e;
        __syncthreads();
        if (t == 0) base_sh = base + pad;
        __syncthreads();
    }
    if (t == 0) {
        tt[b] = base_sh >> 7;
        pt[b] = base_sh;
    }
}

// ---------------- merged dense GEMM: z=0..7 -> K (normal C), z=8..15 -> V (transposed C) ----------------
__global__ __launch_bounds__(256)
void gemm_kv_kernel(const u16* __restrict__ A,
                    const u16* __restrict__ Wkv,
                    u16* __restrict__ CK, u16* __restrict__ CV,
                    const float* __restrict__ biasKV) {
    __shared__ __align__(16) u16 As[2][128 * 64];
    __shared__ __align__(16) u16 Bs[2][128 * 64];
    const int z = blockIdx.z;
    const u16* Bb = Wkv + (long)z * 262144 + (long)blockIdx.x * 128 * 512;

    const int tid = threadIdx.x;
    const int w = tid >> 6, lane = tid & 63;
    const int wy = w >> 1, wx = w & 1;
    const int quad = lane >> 4, mrow = lane & 15;

    long arow[4];
    #pragma unroll
    for (int j = 0; j < 4; ++j) arow[j] = (long)blockIdx.y * 128 + ((j * 256 + tid) >> 3);

    floatx4 acc[4][4];
    #pragma unroll
    for (int i = 0; i < 4; i++)
        #pragma unroll
        for (int j = 0; j < 4; j++)
            acc[i][j] = floatx4{0.f, 0.f, 0.f, 0.f};

    stage64(A, 512, arow, Bb, 512, 0, tid, As[0], Bs[0]);
    for (int it = 0; it < 8; ++it) {
        const int cur = it & 1;
        __syncthreads();
        if (it + 1 < 8)
            stage64(A, 512, arow, Bb, 512, (it + 1) << 6, tid, As[1 - cur], Bs[1 - cur]);
        compute64(As[cur], Bs[cur], wy, wx, quad, mrow, acc);
    }

    const float* biasb = biasKV + (long)z * 512 + blockIdx.x * 128;
    if (z >= 8) {   // V: transposed C into VT layout
        u16* Cb = CV + (long)(z - 8) * 2097152;
        #pragma unroll
        for (int ni = 0; ni < 4; ni++) {
            const int colt = wx * 64 + ni * 16 + mrow;
            const int n = blockIdx.x * 128 + colt;
            float bv = biasb[colt];
            #pragma unroll
            for (int mi = 0; mi < 4; mi++) {
                #pragma unroll
                for (int r = 0; r < 4; r++) {
                    const int m = blockIdx.y * 128 + wy * 64 + mi * 16 + quad * 4 + r;
                    float v = acc[mi][ni][r] + bv;
                    long addr = ((long)(((m >> 10) << 2) + (n >> 7)) * 128 + (n & 127)) * 1024 + (m & 1023);
                    Cb[addr] = f2bf_bits(v);
                }
            }
        }
    } else {        // K: normal row-major C
        u16* Cb = CK + (long)z * 2097152 + (long)blockIdx.y * 128 * 512 + blockIdx.x * 128;
        #pragma unroll
        for (int ni = 0; ni < 4; ni++) {
            const int col = wx * 64 + ni * 16 + mrow;
            float bv = biasb[col];
            #pragma unroll
            for (int mi = 0; mi < 4; mi++) {
                #pragma unroll
                for (int r = 0; r < 4; r++) {
                    const int row = wy * 64 + mi * 16 + quad * 4 + r;
                    Cb[(long)row * 512 + col] = f2bf_bits(acc[mi][ni][r] + bv);
                }
            }
        }
    }
}

// ---------------- fused attention: R2 structure + raw barriers with counted vmcnt ----------------
// grid x=24 (packed tiles), y=16 (b*4+h). OC block-exclusively aliases QP (read in prologue).
// Steady state per 128-key step kt:
//   [wait vmcnt(0) lgkm(0); BARRIER]  <- K(kt) prefetched a full PV phase earlier: cheap
//   issue V(kt) (8 gload_lds)  |  QK(kt) 64 MFMA  |  exp  |  issue K(kt+1) (8 gload_lds) | write P
//   [wait vmcnt(8) lgkm(0); BARRIER]  <- drains V(kt) ONLY; K(kt+1) stays in flight
//   PV(kt) 64 MFMA
__global__ __launch_bounds__(256, 1)
void attn_fused_kernel(const u16* __restrict__ QP, const u16* __restrict__ Km,
                       const u16* __restrict__ VT, u16* __restrict__ OC,
                       const int* __restrict__ tmap, const int* __restrict__ tt, float alpha) {
    const int tile = blockIdx.x;
    const int bh = blockIdx.y;
    const int b = bh >> 2, h = bh & 3;
    if (tile >= tt[b]) return;
    const int e = tmap[b * 32 + tile];

    __shared__ __align__(16) u16 Kb[2][128 * 128];  // K(kt) double buffer (two 64-d halves each)
    __shared__ __align__(16) u16 Vb[128 * 128];     // V tile (two 64-key halves)
    __shared__ __align__(16) u16 Ps[2][128 * 64];   // Q staging (prologue), then P
    __shared__ float rs_sh[2][128];

    const int tid = threadIdx.x;
    const int w = tid >> 6, lane = tid & 63;
    const int wy = w >> 1, wx = w & 1;
    const int quad = lane >> 4, mrow = lane & 15;

    const u16* Qbase = QP + ((long)b * 3072 + tile * 128) * 512 + h * 128;
    const u16* Kbase = Km + ((long)e * 4096 + b * 1024) * 512 + h * 128;
    const u16* Vbase = VT + ((long)e * 16 + bh) * 131072;

    // ---- prologue: Q -> registers (staged through Ps), full drains (prologue only) ----
    stage_one(Qbase, 512, tid, Ps[0]);
    stage_one(Qbase + 64, 512, tid, Ps[1]);
    __syncthreads();
    bfv8 qf[2][2][4];
    #pragma unroll
    for (int c = 0; c < 2; c++)
        #pragma unroll
        for (int kk = 0; kk < 2; kk++)
            #pragma unroll
            for (int ni = 0; ni < 4; ni++) {
                const int r = wx * 64 + ni * 16 + mrow;
                const int slot = (kk * 4 + quad) ^ (r & 7);
                qf[c][kk][ni] = *(const bfv8*)&Ps[c][r * 64 + slot * 8];
            }
    __syncthreads();

    floatx4 acc_o[4][4];
    float rsum[4];
    #pragma unroll
    for (int i = 0; i < 4; i++) {
        rsum[i] = 0.f;
        #pragma unroll
        for (int j = 0; j < 4; j++) acc_o[i][j] = floatx4{0.f, 0.f, 0.f, 0.f};
    }

    // prefetch K(0) into Kb[0]  (8 gload_lds outstanding entering the loop)
    stage_one(Kbase, 512, tid, Kb[0]);
    stage_one(Kbase + 64, 512, tid, Kb[0] + 8192);

    for (int kt = 0; kt < 8; ++kt) {
        // BARRIER 1: K(kt) landed; all waves past PV(kt-1)
        asm volatile("s_waitcnt vmcnt(0) lgkmcnt(0)" ::: "memory");
        __builtin_amdgcn_s_barrier();
        __builtin_amdgcn_sched_barrier(0);

        // issue V(kt): 8 gload_lds (oldest outstanding group) — lands under QK
        stage_one(Vbase + kt * 128,      1024, tid, Vb);
        stage_one(Vbase + kt * 128 + 64, 1024, tid, Vb + 8192);

        // QK(kt): S^T[key 128][q 128]
        const u16* K0 = Kb[kt & 1];
        floatx4 acc_s[4][4];
        #pragma unroll
        for (int i = 0; i < 4; i++)
            #pragma unroll
            for (int j = 0; j < 4; j++) acc_s[i][j] = floatx4{0.f, 0.f, 0.f, 0.f};
        computeQK(K0,        qf[0], wy, quad, mrow, acc_s);
        computeQK(K0 + 8192, qf[1], wy, quad, mrow, acc_s);

        // exp + per-lane row sums (queries are lane-local in S^T layout)
        #pragma unroll
        for (int mi = 0; mi < 4; mi++)
            #pragma unroll
            for (int ni = 0; ni < 4; ni++)
                #pragma unroll
                for (int r = 0; r < 4; r++) {
                    float p = __expf(acc_s[mi][ni][r] * alpha);
                    acc_s[mi][ni][r] = p;
                    rsum[ni] += p;
                }

        // issue K(kt+1): 8 gload_lds (newer group) — stays in flight across BARRIER 2
        const int ktn = (kt < 7) ? kt + 1 : 7;
        stage_one(Kbase + (long)ktn * 128 * 512,      512, tid, Kb[(kt + 1) & 1]);
        stage_one(Kbase + (long)ktn * 128 * 512 + 64, 512, tid, Kb[(kt + 1) & 1] + 8192);

        // write P into Ps as B-operand [query][key-chunk], chunk = wy half
        u16* Pw = Ps[wy];
        #pragma unroll
        for (int mi = 0; mi < 4; mi++) {
            const int sb = mi * 2 + (quad >> 1);
            #pragma unroll
            for (int ni = 0; ni < 4; ni++) {
                const int q = wx * 64 + ni * 16 + mrow;
                u16* pr = Pw + q * 64 + (sb ^ (q & 7)) * 8 + (quad & 1) * 4;
                uint2 pk;
                pk.x = (uint32_t)f2bf_bits(acc_s[mi][ni][0]) | ((uint32_t)f2bf_bits(acc_s[mi][ni][1]) << 16);
                pk.y = (uint32_t)f2bf_bits(acc_s[mi][ni][2]) | ((uint32_t)f2bf_bits(acc_s[mi][ni][3]) << 16);
                *(uint2*)pr = pk;
            }
        }

        // BARRIER 2: V(kt) landed (counted — K(kt+1)'s 8 loads keep flying), P visible
        asm volatile("s_waitcnt vmcnt(8) lgkmcnt(0)" ::: "memory");
        __builtin_amdgcn_s_barrier();
        __builtin_amdgcn_sched_barrier(0);

        // PV(kt): O^T += V^T @ P^T
        compute64(Vb,        Ps[0], wy, wx, quad, mrow, acc_o);
        compute64(Vb + 8192, Ps[1], wy, wx, quad, mrow, acc_o);
    }

    // epilogue: full drain (leftover clamped K loads), then rowsum reduce + normalize + store
    __syncthreads();
    #pragma unroll
    for (int ni = 0; ni < 4; ni++) {
        float v = rsum[ni];
        v += __shfl_xor(v, 16, 64);
        v += __shfl_xor(v, 32, 64);
        if (quad == 0) rs_sh[wy][wx * 64 + ni * 16 + mrow] = v;
    }
    __syncthreads();
    u16* Cb = OC + ((long)b * 3072 + tile * 128) * 512 + h * 128;
    #pragma unroll
    for (int ni = 0; ni < 4; ni++) {
        const int q = wx * 64 + ni * 16 + mrow;
        const float inv = 1.f / (rs_sh[0][q] + rs_sh[1][q]);
        #pragma unroll
        for (int mi = 0; mi < 4; mi++) {
            ushort4 st;
            st.x = f2bf_bits(acc_o[mi][ni][0] * inv);
            st.y = f2bf_bits(acc_o[mi][ni][1] * inv);
            st.z = f2bf_bits(acc_o[mi][ni][2] * inv);
            st.w = f2bf_bits(acc_o[mi][ni][3] * inv);
            *(ushort4*)(Cb + (long)q * 512 + wy * 64 + mi * 16 + quad * 4) = st;
        }
    }
}

// ---------------- packed GEMM (Qp / Wo / FFN1 / FFN2): per-tile expert weights ----------------
// grid x = N/128, y = 96 (b = y/24, tile = y%24); GATHER: A rows via prix
template<bool RELU, bool GATHER>
__global__ __launch_bounds__(256)
void gemm_packed_kernel(const u16* __restrict__ A, int lda,
                        const u16* __restrict__ B, int ldb, long sBe,
                        u16* __restrict__ C, int ldc,
                        const float* __restrict__ bias, long sBiasE,
                        const int* __restrict__ tmap, const int* __restrict__ tt, int K,
                        const int* __restrict__ prix) {
    const int b = blockIdx.y / 24, tile = blockIdx.y % 24;
    if (tile >= tt[b]) return;
    const int e = tmap[b * 32 + tile];
    __shared__ __align__(16) u16 As[2][128 * 64];
    __shared__ __align__(16) u16 Bs[2][128 * 64];
    const long rbase = (long)b * 3072 + tile * 128;
    const u16* Ab = GATHER ? A : A + rbase * lda;
    const u16* Bb = B + (long)e * sBe + (long)blockIdx.x * 128 * ldb;

    const int tid = threadIdx.x;
    const int w = tid >> 6, lane = tid & 63;
    const int wy = w >> 1, wx = w & 1;
    const int quad = lane >> 4, mrow = lane & 15;

    long arow[4];
    #pragma unroll
    for (int j = 0; j < 4; ++j) {
        const int lr = (j * 256 + tid) >> 3;
        arow[j] = GATHER ? (long)prix[b * 3072 + tile * 128 + lr] : (long)lr;
    }

    floatx4 acc[4][4];
    #pragma unroll
    for (int i = 0; i < 4; i++)
        #pragma unroll
        for (int j = 0; j < 4; j++)
            acc[i][j] = floatx4{0.f, 0.f, 0.f, 0.f};

    const int nk = K >> 6;
    stage64(Ab, lda, arow, Bb, ldb, 0, tid, As[0], Bs[0]);
    for (int it = 0; it < nk; ++it) {
        const int cur = it & 1;
        __syncthreads();
        if (it + 1 < nk)
            stage64(Ab, lda, arow, Bb, ldb, (it + 1) << 6, tid, As[1 - cur], Bs[1 - cur]);
        compute64(As[cur], Bs[cur], wy, wx, quad, mrow, acc);
    }

    u16* Cb = C + rbase * ldc + (long)blockIdx.x * 128;
    const float* biasb = bias + (long)e * sBiasE + blockIdx.x * 128;
    #pragma unroll
    for (int ni = 0; ni < 4; ni++) {
        const int col = wx * 64 + ni * 16 + mrow;
        float bv = biasb[col];
        #pragma unroll
        for (int mi = 0; mi < 4; mi++) {
            #pragma unroll
            for (int r = 0; r < 4; r++) {
                const int row = wy * 64 + mi * 16 + quad * 4 + r;
                float v = acc[mi][ni][r] + bv;
                if (RELU) v = fmaxf(v, 0.f);
                Cb[(long)row * ldc + col] = f2bf_bits(v);
            }
        }
    }
}

// ---------------- LN1 on packed rows ----------------
__global__ __launch_bounds__(128)
void ln1_kernel(const float* __restrict__ x, const u16* __restrict__ tc,
                const int* __restrict__ prix, const int* __restrict__ act,
                const int* __restrict__ tmap, const int* __restrict__ pt,
                const float* __restrict__ s_all, const float* __restrict__ b_all,
                u16* __restrict__ hb) {
    int blk = blockIdx.x;
    int b = blk / 3072, pslot = blk % 3072;
    if (pslot >= pt[b]) return;
    long row = (long)b * 3072 + pslot;
    int tid = threadIdx.x, w = tid >> 6, lane = tid & 63;
    if (!act[row]) {
        *(ushort4*)(hb + row * 512 + tid * 4) = make_ushort4(0, 0, 0, 0);
        return;
    }
    int r = prix[row];
    int e = tmap[b * 32 + (pslot >> 7)];
    float4 xv = *(const float4*)(x + (long)r * 512 + tid * 4);
    ushort4 tu = *(const ushort4*)(tc + row * 512 + tid * 4);
    float v[4] = {xv.x + bf_bits2f(tu.x), xv.y + bf_bits2f(tu.y),
                  xv.z + bf_bits2f(tu.z), xv.w + bf_bits2f(tu.w)};
    float sum = v[0] + v[1] + v[2] + v[3];
    #pragma unroll
    for (int o = 32; o; o >>= 1) sum += __shfl_down(sum, o, 64);
    __shared__ float sh[4];
    if (lane == 0) sh[w] = sum;
    __syncthreads();
    float mu = (sh[0] + sh[1]) * (1.f / 512.f);
    float sq = 0.f;
    #pragma unroll
    for (int j = 0; j < 4; j++) { float d = v[j] - mu; sq += d * d; }
    #pragma unroll
    for (int o = 32; o; o >>= 1) sq += __shfl_down(sq, o, 64);
    if (lane == 0) sh[2 + w] = sq;
    __syncthreads();
    float inv = 1.f / sqrtf((sh[2] + sh[3]) * (1.f / 512.f) + 1e-5f);
    float4 sv = *(const float4*)(s_all + e * 512 + tid * 4);
    float4 bv = *(const float4*)(b_all + e * 512 + tid * 4);
    ushort4 ub;
    ub.x = f2bf_bits((v[0] - mu) * inv * sv.x + bv.x);
    ub.y = f2bf_bits((v[1] - mu) * inv * sv.y + bv.y);
    ub.z = f2bf_bits((v[2] - mu) * inv * sv.z + bv.z);
    ub.w = f2bf_bits((v[3] - mu) * inv * sv.w + bv.w);
    *(ushort4*)(hb + row * 512 + tid * 4) = ub;
}

// ---------------- LN2 + weighted accumulate over all 8 experts ----------------
__global__ __launch_bounds__(128)
void ln2acc_kernel(const u16* __restrict__ hb, const u16* __restrict__ t2,
                   const float* __restrict__ s_all, const float* __restrict__ b_all,
                   const float* __restrict__ rw, const int* __restrict__ smap,
                   float* __restrict__ out) {
    long r = blockIdx.x;
    int b = (int)(r >> 10);
    int tid = threadIdx.x, w = tid >> 6, lane = tid & 63;
    __shared__ float sh[4];
    float4 acc = make_float4(0.f, 0.f, 0.f, 0.f);
    for (int e = 0; e < 8; e++) {
        int ps = smap[r * 8 + e];
        if (ps >= 0) {   // block-uniform
            float wgt = rw[r * 8 + e];
            long row = (long)b * 3072 + ps;
            ushort4 hu = *(const ushort4*)(hb + row * 512 + tid * 4);
            ushort4 fu = *(const ushort4*)(t2 + row * 512 + tid * 4);
            float v[4] = {bf_bits2f(hu.x) + bf_bits2f(fu.x), bf_bits2f(hu.y) + bf_bits2f(fu.y),
                          bf_bits2f(hu.z) + bf_bits2f(fu.z), bf_bits2f(hu.w) + bf_bits2f(fu.w)};
            float sum = v[0] + v[1] + v[2] + v[3];
            #pragma unroll
            for (int o = 32; o; o >>= 1) sum += __shfl_down(sum, o, 64);
            if (lane == 0) sh[w] = sum;
            __syncthreads();
            float mu = (sh[0] + sh[1]) * (1.f / 512.f);
            float sq = 0.f;
            #pragma unroll
            for (int j = 0; j < 4; j++) { float d = v[j] - mu; sq += d * d; }
            #pragma unroll
            for (int o = 32; o; o >>= 1) sq += __shfl_down(sq, o, 64);
            if (lane == 0) sh[2 + w] = sq;
            __syncthreads();
            float inv = 1.f / sqrtf((sh[2] + sh[3]) * (1.f / 512.f) + 1e-5f);
            float4 sv = *(const float4*)(s_all + e * 512 + tid * 4);
            float4 bv = *(const float4*)(b_all + e * 512 + tid * 4);
            acc.x += wgt * ((v[0] - mu) * inv * sv.x + bv.x);
            acc.y += wgt * ((v[1] - mu) * inv * sv.y + bv.y);
            acc.z += wgt * ((v[2] - mu) * inv * sv.z + bv.z);
            acc.w += wgt * ((v[3] - mu) * inv * sv.w + bv.w);
            __syncthreads();
        }
    }
    *(float4*)(out + r * 512 + tid * 4) = acc;
}

// ---------------- workspace layout (bytes), ws_size = 256 MiB ----------------
static const size_t WB_B   = 0;           // 48 MiB: wq,wk,wv,wo (8x262144 each), w1 (8x1048576), w2 (8x1048576)
static const size_t RW_B   = 50331648;    // f32 [4096][8]
static const size_t PB_B   = 50462720;    // f32 [3][8][512]
static const size_t TT_B   = 50511872;    // i32[4] tiles per b
static const size_t PT_B   = 50511888;    // i32[4] packed rows per b
static const size_t TMAP_B = 50511904;    // i32 [4][32]
static const size_t PRIX_B = 50512416;    // i32 [4][3072]
static const size_t ACT_B  = 50561568;    // i32 [4][3072]
static const size_t SMAP_B = 50610720;    // i32 [4096][8]
static const size_t XB_B   = 50741792;    // bf16 [4096][512]
static const size_t Q8_B   = 54936096;    // bf16 packed Q [4][3072][512] (12.6 MiB)
static const size_t K8_B   = 88490528;    // bf16 [8][4096][512] (32 MiB)
static const size_t VT_B   = 122044960;   // bf16 [8][16][128][1024] (32 MiB)
static const size_t S_B    = 155599392;   // scratch region (FFN mid), 96 MiB
static const size_t OC_B   = Q8_B;        // fused attn out: block-exclusive alias of QP
static const size_t TC_B   = K8_B;        // bf16 [4][3072][512] — K dead after attn
static const size_t HB_B   = Q8_B;        // LN1 out — OC dead after Wo
static const size_t MID_B  = S_B;         // bf16 [4][3072][2048] (50 MB)
static const size_t T2_B   = VT_B;        // bf16 [4][3072][512] — VT dead after attn

extern "C" void kernel_launch(void* const* d_in, const int* in_sizes, int n_in,
                              void* d_out, int out_size, void* d_ws, size_t ws_size,
                              hipStream_t stream) {
    const float* x      = (const float*)d_in[0];
    const float* gate_w = (const float*)d_in[1];
    const float* gate_b = (const float*)d_in[2];
    const float* ln1_s  = (const float*)d_in[3];
    const float* ln1_b  = (const float*)d_in[4];
    const float* ln2_s  = (const float*)d_in[5];
    const float* ln2_b  = (const float*)d_in[6];
    const float* wq = (const float*)d_in[7];
    const float* wk = (const float*)d_in[8];
    const float* wv = (const float*)d_in[9];
    const float* wo = (const float*)d_in[10];
    const float* bo = (const float*)d_in[14];
    const float* w1 = (const float*)d_in[15];
    const float* b1 = (const float*)d_in[16];
    const float* w2 = (const float*)d_in[17];
    const float* b2 = (const float*)d_in[18];
    float* out = (float*)d_out;

    char* ws = (char*)d_ws;
    u16*   WB   = (u16*)(ws + WB_B);
    float* RW   = (float*)(ws + RW_B);
    float* PB   = (float*)(ws + PB_B);
    int*   TT   = (int*)(ws + TT_B);
    int*   PT   = (int*)(ws + PT_B);
    int*   TMAP = (int*)(ws + TMAP_B);
    int*   PRIX = (int*)(ws + PRIX_B);
    int*   ACT  = (int*)(ws + ACT_B);
    int*   SMAP = (int*)(ws + SMAP_B);
    u16*   XB   = (u16*)(ws + XB_B);
    u16*   QP   = (u16*)(ws + Q8_B);
    u16*   K8   = (u16*)(ws + K8_B);
    u16*   VT8  = (u16*)(ws + VT_B);
    u16*   OC   = (u16*)(ws + OC_B);
    u16*   TC   = (u16*)(ws + TC_B);
    u16*   HB   = (u16*)(ws + HB_B);
    u16*   MID  = (u16*)(ws + MID_B);
    u16*   T2   = (u16*)(ws + T2_B);

    // ---- setup ----
    cast_bf16_kernel<<<dim3(2096), 256, 0, stream>>>(x, XB, 4096 * 512 / 4,
                                                     (const float*)d_in[11], (const float*)d_in[12],
                                                     (const float*)d_in[13], PB);
    transpose_cast4_kernel<<<dim3(16,16,32), dim3(32,8), 0, stream>>>(wq, wk, wv, wo, WB);
    transpose_cast_kernel<<<dim3(64,16,8), dim3(32,8), 0, stream>>>(w1, WB + 8388608,  512,  2048, 1048576, 1048576);
    transpose_cast_kernel<<<dim3(16,64,8), dim3(32,8), 0, stream>>>(w2, WB + 16777216, 2048, 512,  1048576, 1048576);
    router_kernel<<<4096, 512, 0, stream>>>(x, gate_w, gate_b, RW, out + 2097152);
    build_lists_kernel<<<4, 256, 0, stream>>>(RW, PRIX, ACT, SMAP, TMAP, TT, PT);

    const float isq = 0.08838834764831845f;  // 1/sqrt(128)

    // ---- K + V for all 8 experts in one launch (z<8: K normal, z>=8: V transposed) ----
    gemm_kv_kernel<<<dim3(4,32,16), 256, 0, stream>>>(XB, WB + 2097152, K8, VT8, PB + 4096);
    // ---- Q only for packed (routed) rows, gathered from x ----
    gemm_packed_kernel<false, true><<<dim3(4,96), 256, 0, stream>>>(
        XB, 512, WB, 512, 262144, QP, 512, PB, 512, TMAP, TT, 512, PRIX);

    // ---- fused attention (counted-vmcnt pipeline, 8 x 128-key steps) ----
    attn_fused_kernel<<<dim3(24, 16), 256, 0, stream>>>(QP, K8, VT8, OC, TMAP, TT, isq);

    // ---- Wo ----
    gemm_packed_kernel<false, false><<<dim3(4,96), 256, 0, stream>>>(
        OC, 512, WB + 6291456, 512, 262144, TC, 512, bo, 512, TMAP, TT, 512, nullptr);
    // ---- LN1 ----
    ln1_kernel<<<12288, 128, 0, stream>>>(x, TC, PRIX, ACT, TMAP, PT, ln1_s, ln1_b, HB);
    // ---- FFN1 ----
    gemm_packed_kernel<true, false><<<dim3(16,96), 256, 0, stream>>>(
        HB, 512, WB + 8388608, 512, 1048576, MID, 2048, b1, 2048, TMAP, TT, 512, nullptr);
    // ---- FFN2 ----
    gemm_packed_kernel<false, false><<<dim3(4,96), 256, 0, stream>>>(
        MID, 2048, WB + 16777216, 2048, 1048576, T2, 512, b2, 512, TMAP, TT, 2048, nullptr);
    // ---- LN2 + routing-weighted accumulate ----
    ln2acc_kernel<<<4096, 128, 0, stream>>>(HB, T2, ln2_s, ln2_b, RW, SMAP, out);
}

// Round 7
// 434.757 us; speedup vs baseline: 1.1578x; 1.0574x over previous
//
#include <hip/hip_runtime.h>
#include <hip/hip_bf16.h>
#include <stdint.h>

using u16 = unsigned short;
typedef float floatx4 __attribute__((ext_vector_type(4)));
typedef __bf16 bfv8 __attribute__((ext_vector_type(8)));

#define AS1 __attribute__((address_space(1)))
#define AS3 __attribute__((address_space(3)))

__device__ __forceinline__ u16 f2bf_bits(float f) {
    __hip_bfloat16 h = __float2bfloat16(f);
    u16 u;
    __builtin_memcpy(&u, &h, 2);
    return u;
}
__device__ __forceinline__ float bf_bits2f(u16 u) {
    __hip_bfloat16 h;
    __builtin_memcpy(&h, &u, 2);
    return __bfloat162float(h);
}
__device__ __forceinline__ void gload_lds16(const void* g, void* l) {
    __builtin_amdgcn_global_load_lds((AS1 void*)(uintptr_t)g, (AS3 void*)l, 16, 0, 0);
}

// ---- BK=64 tile staging (dbuf), XOR-swizzled chunks ----
__device__ __forceinline__ void stage64(const u16* __restrict__ Abase, long lda, const long* arow,
                                        const u16* __restrict__ Bb, long ldb, int k0, int tid,
                                        u16* Ad, u16* Bd) {
    #pragma unroll
    for (int j = 0; j < 4; ++j) {
        const int q   = j * 256 + tid;
        const int row = q >> 3;
        const int cg  = (q & 7) ^ (row & 7);
        gload_lds16(Abase + arow[j] * lda + k0 + cg * 8, Ad + q * 8);
        gload_lds16(Bb + (long)row * ldb + k0 + cg * 8, Bd + q * 8);
    }
}
// stage a single 128x64 chunk (contiguous rows)
__device__ __forceinline__ void stage_one(const u16* __restrict__ base, long ld, int tid, u16* dst) {
    #pragma unroll
    for (int j = 0; j < 4; ++j) {
        const int q   = j * 256 + tid;
        const int row = q >> 3;
        const int cg  = (q & 7) ^ (row & 7);
        gload_lds16(base + (long)row * ld + cg * 8, dst + q * 8);
    }
}
__device__ __forceinline__ void compute64(const u16* Ab, const u16* Bb, int wy, int wx,
                                          int quad, int mrow, floatx4 acc[4][4]) {
    #pragma unroll
    for (int kk = 0; kk < 2; ++kk) {
        bfv8 af[4], bf[4];
        #pragma unroll
        for (int mi = 0; mi < 4; mi++) {
            const int r = wy * 64 + mi * 16 + mrow;
            const int slot = (kk * 4 + quad) ^ (r & 7);
            af[mi] = *(const bfv8*)&Ab[r * 64 + slot * 8];
        }
        #pragma unroll
        for (int ni = 0; ni < 4; ni++) {
            const int r = wx * 64 + ni * 16 + mrow;
            const int slot = (kk * 4 + quad) ^ (r & 7);
            bf[ni] = *(const bfv8*)&Bb[r * 64 + slot * 8];
        }
        #pragma unroll
        for (int mi = 0; mi < 4; mi++)
            #pragma unroll
            for (int ni = 0; ni < 4; ni++)
                acc[mi][ni] = __builtin_amdgcn_mfma_f32_16x16x32_bf16(af[mi], bf[ni], acc[mi][ni], 0, 0, 0);
    }
}
// A from LDS (K-tile rows=keys), B from registers (Q fragments)
__device__ __forceinline__ void computeQK(const u16* Kb, const bfv8 qf[2][4], int wy,
                                          int quad, int mrow, floatx4 acc[4][4]) {
    #pragma unroll
    for (int kk = 0; kk < 2; ++kk) {
        bfv8 af[4];
        #pragma unroll
        for (int mi = 0; mi < 4; mi++) {
            const int r = wy * 64 + mi * 16 + mrow;
            const int slot = (kk * 4 + quad) ^ (r & 7);
            af[mi] = *(const bfv8*)&Kb[r * 64 + slot * 8];
        }
        #pragma unroll
        for (int mi = 0; mi < 4; mi++)
            #pragma unroll
            for (int ni = 0; ni < 4; ni++)
                acc[mi][ni] = __builtin_amdgcn_mfma_f32_16x16x32_bf16(af[mi], qf[kk][ni], acc[mi][ni], 0, 0, 0);
    }
}

// ---------------- cast fp32 -> bf16 (+ fused bias pack in tail blocks) ----------------
__global__ void cast_bf16_kernel(const float* __restrict__ in, u16* __restrict__ out, int n4,
                                 const float* __restrict__ bq, const float* __restrict__ bk,
                                 const float* __restrict__ bv, float* __restrict__ pb) {
    if (blockIdx.x >= 2048) {
        int j = (blockIdx.x - 2048) * 256 + threadIdx.x;  // 0..12287
        const float* s = j < 4096 ? bq : (j < 8192 ? bk : bv);
        pb[j] = s[j & 4095];
        return;
    }
    int i = blockIdx.x * blockDim.x + threadIdx.x;
    if (i >= n4) return;
    float4 v = ((const float4*)in)[i];
    ushort4 o;
    o.x = f2bf_bits(v.x); o.y = f2bf_bits(v.y); o.z = f2bf_bits(v.z); o.w = f2bf_bits(v.w);
    ((ushort4*)out)[i] = o;
}

// ---------------- transpose+cast fp32 [z][R][C] -> bf16 [z][C][R] ----------------
__global__ void transpose_cast_kernel(const float* __restrict__ src, u16* __restrict__ dst,
                                      int R, int C, long sSrc, long sDst) {
    __shared__ float tile[32][33];
    const float* s = src + (long)blockIdx.z * sSrc;
    u16* d = dst + (long)blockIdx.z * sDst;
    int c0 = blockIdx.x * 32, r0 = blockIdx.y * 32;
    int tx = threadIdx.x, ty = threadIdx.y;
    #pragma unroll
    for (int i = 0; i < 4; i++)
        tile[ty + 8*i][tx] = s[(long)(r0 + ty + 8*i) * C + c0 + tx];
    __syncthreads();
    #pragma unroll
    for (int i = 0; i < 4; i++)
        d[(long)(c0 + ty + 8*i) * R + r0 + tx] = f2bf_bits(tile[tx][ty + 8*i]);
}

// ---------------- merged transpose+cast for wq,wk,wv,wo (512x512 each, z=0..31) ----------------
__global__ void transpose_cast4_kernel(const float* __restrict__ w0, const float* __restrict__ w1p,
                                       const float* __restrict__ w2p, const float* __restrict__ w3p,
                                       u16* __restrict__ dst) {
    __shared__ float tile[32][33];
    int z = blockIdx.z;
    const float* s = (z < 8 ? w0 : z < 16 ? w1p : z < 24 ? w2p : w3p) + (long)(z & 7) * 262144;
    u16* d = dst + (long)z * 262144;
    int c0 = blockIdx.x * 32, r0 = blockIdx.y * 32;
    int tx = threadIdx.x, ty = threadIdx.y;
    #pragma unroll
    for (int i = 0; i < 4; i++)
        tile[ty + 8*i][tx] = s[(long)(r0 + ty + 8*i) * 512 + c0 + tx];
    __syncthreads();
    #pragma unroll
    for (int i = 0; i < 4; i++)
        d[(long)(c0 + ty + 8*i) * 512 + r0 + tx] = f2bf_bits(tile[tx][ty + 8*i]);
}

// ---------------- router ----------------
__global__ __launch_bounds__(512)
void router_kernel(const float* __restrict__ x, const float* __restrict__ gw,
                   const float* __restrict__ gb, float* __restrict__ rw,
                   float* __restrict__ logits_out) {
    int row = blockIdx.x;
    int w = threadIdx.x >> 6;
    int lane = threadIdx.x & 63;
    const float* xr = x + (long)row * 512;
    float sum = 0.f;
    #pragma unroll
    for (int i = 0; i < 8; i++) {
        int d = lane + 64 * i;
        sum += xr[d] * gw[d * 8 + w];
    }
    #pragma unroll
    for (int o = 32; o; o >>= 1) sum += __shfl_down(sum, o, 64);
    __shared__ float lg[8];
    if (lane == 0) lg[w] = sum + gb[w];
    __syncthreads();
    if (threadIdx.x == 0) {
        float l[8];
        #pragma unroll
        for (int e = 0; e < 8; e++) l[e] = lg[e];
        int i1 = 0;
        for (int e = 1; e < 8; e++) if (l[e] > l[i1]) i1 = e;
        int i2 = -1;
        for (int e = 0; e < 8; e++) { if (e == i1) continue; if (i2 < 0 || l[e] > l[i2]) i2 = e; }
        for (int e = 0; e < 8; e++) {
            float v = (e == i1 || e == i2) ? (l[e] > 0.f ? l[e] : 0.f) : 0.f;
            float r = 0.f, mem = v;
            #pragma unroll
            for (int lvl = 0; lvl < 4; lvl++) {
                float thr = 4.0f / (float)(1 << lvl);
                if (mem >= thr) { r += thr; mem -= thr; }
            }
            rw[(long)row * 8 + e] = r;
            logits_out[(long)row * 8 + e] = l[e];
        }
    }
}

// ---------------- build packed row space: per b, experts packed back-to-back ----------------
__global__ __launch_bounds__(256)
void build_lists_kernel(const float* __restrict__ rw, int* __restrict__ prix,
                        int* __restrict__ act, int* __restrict__ smap,
                        int* __restrict__ tmap, int* __restrict__ tt, int* __restrict__ pt) {
    int b = blockIdx.x;
    int t = threadIdx.x, wv = t >> 6, lane = t & 63;
    __shared__ int wsum[4];
    __shared__ int base_sh;
    if (t == 0) base_sh = 0;
    __syncthreads();
    for (int e = 0; e < 8; e++) {
        int r0 = b * 1024 + t * 4;
        int f[4], c = 0;
        #pragma unroll
        for (int i = 0; i < 4; i++) {
            f[i] = (rw[(long)(r0 + i) * 8 + e] != 0.f) ? 1 : 0;
            c += f[i];
        }
        int incl = c;
        #pragma unroll
        for (int o = 1; o < 64; o <<= 1) {
            int n = __shfl_up(incl, o, 64);
            if (lane >= o) incl += n;
        }
        if (lane == 63) wsum[wv] = incl;
        __syncthreads();
        int woff = 0;
        #pragma unroll
        for (int k = 0; k < 4; k++) if (k < wv) woff += wsum[k];
        int tot = wsum[0] + wsum[1] + wsum[2] + wsum[3];
        int excl = incl - c + woff;
        int base = base_sh;
        int slot = excl;
        #pragma unroll
        for (int i = 0; i < 4; i++) {
            int r = r0 + i;
            if (f[i]) {
                int ps = base + slot;
                prix[b * 3072 + ps] = r;
                act[b * 3072 + ps] = 1;
                smap[(long)r * 8 + e] = ps;
                slot++;
            } else {
                smap[(long)r * 8 + e] = -1;
            }
        }
        int pad = (tot + 127) & ~127;
        for (int s = tot + t; s < pad; s += 256) {
            prix[b * 3072 + base + s] = b * 1024;
            act[b * 3072 + base + s] = 0;
        }
        for (int k = t; k < (pad >> 7); k += 256)
            tmap[b * 32 + (base >> 7) + k] = e;
        __syncthreads();
        if (t == 0) base_sh = base + pad;
        __syncthreads();
    }
    if (t == 0) {
        tt[b] = base_sh >> 7;
        pt[b] = base_sh;
    }
}

// ---------------- merged dense GEMM: z=0..7 -> K (normal C), z=8..15 -> V (transposed C) ----------------
__global__ __launch_bounds__(256)
void gemm_kv_kernel(const u16* __restrict__ A,
                    const u16* __restrict__ Wkv,
                    u16* __restrict__ CK, u16* __restrict__ CV,
                    const float* __restrict__ biasKV) {
    __shared__ __align__(16) u16 As[2][128 * 64];
    __shared__ __align__(16) u16 Bs[2][128 * 64];
    const int z = blockIdx.z;
    const u16* Bb = Wkv + (long)z * 262144 + (long)blockIdx.x * 128 * 512;

    const int tid = threadIdx.x;
    const int w = tid >> 6, lane = tid & 63;
    const int wy = w >> 1, wx = w & 1;
    const int quad = lane >> 4, mrow = lane & 15;

    long arow[4];
    #pragma unroll
    for (int j = 0; j < 4; ++j) arow[j] = (long)blockIdx.y * 128 + ((j * 256 + tid) >> 3);

    floatx4 acc[4][4];
    #pragma unroll
    for (int i = 0; i < 4; i++)
        #pragma unroll
        for (int j = 0; j < 4; j++)
            acc[i][j] = floatx4{0.f, 0.f, 0.f, 0.f};

    stage64(A, 512, arow, Bb, 512, 0, tid, As[0], Bs[0]);
    for (int it = 0; it < 8; ++it) {
        const int cur = it & 1;
        __syncthreads();
        if (it + 1 < 8)
            stage64(A, 512, arow, Bb, 512, (it + 1) << 6, tid, As[1 - cur], Bs[1 - cur]);
        compute64(As[cur], Bs[cur], wy, wx, quad, mrow, acc);
    }

    const float* biasb = biasKV + (long)z * 512 + blockIdx.x * 128;
    if (z >= 8) {   // V: transposed C into VT layout
        u16* Cb = CV + (long)(z - 8) * 2097152;
        #pragma unroll
        for (int ni = 0; ni < 4; ni++) {
            const int colt = wx * 64 + ni * 16 + mrow;
            const int n = blockIdx.x * 128 + colt;
            float bv = biasb[colt];
            #pragma unroll
            for (int mi = 0; mi < 4; mi++) {
                #pragma unroll
                for (int r = 0; r < 4; r++) {
                    const int m = blockIdx.y * 128 + wy * 64 + mi * 16 + quad * 4 + r;
                    float v = acc[mi][ni][r] + bv;
                    long addr = ((long)(((m >> 10) << 2) + (n >> 7)) * 128 + (n & 127)) * 1024 + (m & 1023);
                    Cb[addr] = f2bf_bits(v);
                }
            }
        }
    } else {        // K: normal row-major C
        u16* Cb = CK + (long)z * 2097152 + (long)blockIdx.y * 128 * 512 + blockIdx.x * 128;
        #pragma unroll
        for (int ni = 0; ni < 4; ni++) {
            const int col = wx * 64 + ni * 16 + mrow;
            float bv = biasb[col];
            #pragma unroll
            for (int mi = 0; mi < 4; mi++) {
                #pragma unroll
                for (int r = 0; r < 4; r++) {
                    const int row = wy * 64 + mi * 16 + quad * 4 + r;
                    Cb[(long)row * 512 + col] = f2bf_bits(acc[mi][ni][r] + bv);
                }
            }
        }
    }
}

// ---------------- fused attention: S^T = K@Q^T -> exp -> P@V, no S round trip (R2-proven) ----------------
// grid x=24 (packed tiles), y=16 (b*4+h). OC block-exclusively aliases QP (read-before-write).
__global__ __launch_bounds__(256, 2)
void attn_fused_kernel(const u16* __restrict__ QP, const u16* __restrict__ Km,
                       const u16* __restrict__ VT, u16* __restrict__ OC,
                       const int* __restrict__ tmap, const int* __restrict__ tt, float alpha) {
    const int tile = blockIdx.x;
    const int bh = blockIdx.y;
    const int b = bh >> 2, h = bh & 3;
    if (tile >= tt[b]) return;
    const int e = tmap[b * 32 + tile];

    __shared__ __align__(16) u16 Bs[2][128 * 64];   // K-tile, then V-tile
    __shared__ __align__(16) u16 Ps[2][128 * 64];   // Q staging, then P (B-operand layout)
    __shared__ float rs_sh[2][128];

    const int tid = threadIdx.x;
    const int w = tid >> 6, lane = tid & 63;
    const int wy = w >> 1, wx = w & 1;
    const int quad = lane >> 4, mrow = lane & 15;

    const u16* Qbase = QP + ((long)b * 3072 + tile * 128) * 512 + h * 128;
    const u16* Kbase = Km + ((long)e * 4096 + b * 1024) * 512 + h * 128;
    const u16* Vbase = VT + ((long)e * 16 + bh) * 131072;

    // prologue: stage Q into Ps, then pull fragments into registers
    stage_one(Qbase, 512, tid, Ps[0]);
    stage_one(Qbase + 64, 512, tid, Ps[1]);
    __syncthreads();
    bfv8 qf[2][2][4];
    #pragma unroll
    for (int c = 0; c < 2; c++)
        #pragma unroll
        for (int kk = 0; kk < 2; kk++)
            #pragma unroll
            for (int ni = 0; ni < 4; ni++) {
                const int r = wx * 64 + ni * 16 + mrow;
                const int slot = (kk * 4 + quad) ^ (r & 7);
                qf[c][kk][ni] = *(const bfv8*)&Ps[c][r * 64 + slot * 8];
            }

    floatx4 acc_o[4][4];
    float rsum[4];
    #pragma unroll
    for (int i = 0; i < 4; i++) {
        rsum[i] = 0.f;
        #pragma unroll
        for (int j = 0; j < 4; j++) acc_o[i][j] = floatx4{0.f, 0.f, 0.f, 0.f};
    }

    for (int kt = 0; kt < 8; ++kt) {
        __syncthreads();                       // Bs + Ps free (prev PV reads done; kt=0: qf loaded)
        stage_one(Kbase + (long)kt * 128 * 512,      512, tid, Bs[0]);
        stage_one(Kbase + (long)kt * 128 * 512 + 64, 512, tid, Bs[1]);
        __syncthreads();                       // K ready

        floatx4 acc_s[4][4];
        #pragma unroll
        for (int i = 0; i < 4; i++)
            #pragma unroll
            for (int j = 0; j < 4; j++) acc_s[i][j] = floatx4{0.f, 0.f, 0.f, 0.f};
        computeQK(Bs[0], qf[0], wy, quad, mrow, acc_s);
        computeQK(Bs[1], qf[1], wy, quad, mrow, acc_s);

        // p = exp(alpha*s); per-lane row sums (cols = queries are lane-local in S^T layout)
        #pragma unroll
        for (int mi = 0; mi < 4; mi++)
            #pragma unroll
            for (int ni = 0; ni < 4; ni++)
                #pragma unroll
                for (int r = 0; r < 4; r++) {
                    float p = __expf(acc_s[mi][ni][r] * alpha);
                    acc_s[mi][ni][r] = p;
                    rsum[ni] += p;
                }

        __syncthreads();                       // all QK reads of Bs done
        stage_one(Vbase + kt * 128,      1024, tid, Bs[0]);
        stage_one(Vbase + kt * 128 + 64, 1024, tid, Bs[1]);
        // write P into Ps as B-operand [query][key-chunk], chunk = wy; packed b32 pairs
        u16* Pw = Ps[wy];
        #pragma unroll
        for (int mi = 0; mi < 4; mi++) {
            const int sb = mi * 2 + (quad >> 1);
            #pragma unroll
            for (int ni = 0; ni < 4; ni++) {
                const int q = wx * 64 + ni * 16 + mrow;
                u16* pr = Pw + q * 64 + (sb ^ (q & 7)) * 8 + (quad & 1) * 4;
                #pragma unroll
                for (int r = 0; r < 4; r += 2) {
                    uint32_t pk = (uint32_t)f2bf_bits(acc_s[mi][ni][r]) |
                                  ((uint32_t)f2bf_bits(acc_s[mi][ni][r + 1]) << 16);
                    *(uint32_t*)(pr + r) = pk;
                }
            }
        }
        __syncthreads();                       // V + P ready
        compute64(Bs[0], Ps[0], wy, wx, quad, mrow, acc_o);   // O^T += V^T @ P^T
        compute64(Bs[1], Ps[1], wy, wx, quad, mrow, acc_o);
    }

    // row sums: reduce over quad lanes, then across wy waves via LDS
    #pragma unroll
    for (int ni = 0; ni < 4; ni++) {
        float v = rsum[ni];
        v += __shfl_xor(v, 16, 64);
        v += __shfl_xor(v, 32, 64);
        if (quad == 0) rs_sh[wy][wx * 64 + ni * 16 + mrow] = v;
    }
    __syncthreads();
    u16* Cb = OC + ((long)b * 3072 + tile * 128) * 512 + h * 128;
    #pragma unroll
    for (int ni = 0; ni < 4; ni++) {
        const int q = wx * 64 + ni * 16 + mrow;
        const float inv = 1.f / (rs_sh[0][q] + rs_sh[1][q]);
        #pragma unroll
        for (int mi = 0; mi < 4; mi++) {
            ushort4 st;
            st.x = f2bf_bits(acc_o[mi][ni][0] * inv);
            st.y = f2bf_bits(acc_o[mi][ni][1] * inv);
            st.z = f2bf_bits(acc_o[mi][ni][2] * inv);
            st.w = f2bf_bits(acc_o[mi][ni][3] * inv);
            *(ushort4*)(Cb + (long)q * 512 + wy * 64 + mi * 16 + quad * 4) = st;
        }
    }
}

// ---------------- packed GEMM (Qp / Wo / FFN1 / FFN2): per-tile expert weights ----------------
// grid x = N/128, y = 96 (b = y/24, tile = y%24); GATHER: A rows via prix
template<bool RELU, bool GATHER>
__global__ __launch_bounds__(256)
void gemm_packed_kernel(const u16* __restrict__ A, int lda,
                        const u16* __restrict__ B, int ldb, long sBe,
                        u16* __restrict__ C, int ldc,
                        const float* __restrict__ bias, long sBiasE,
                        const int* __restrict__ tmap, const int* __restrict__ tt, int K,
                        const int* __restrict__ prix) {
    const int b = blockIdx.y / 24, tile = blockIdx.y % 24;
    if (tile >= tt[b]) return;
    const int e = tmap[b * 32 + tile];
    __shared__ __align__(16) u16 As[2][128 * 64];
    __shared__ __align__(16) u16 Bs[2][128 * 64];
    const long rbase = (long)b * 3072 + tile * 128;
    const u16* Ab = GATHER ? A : A + rbase * lda;
    const u16* Bb = B + (long)e * sBe + (long)blockIdx.x * 128 * ldb;

    const int tid = threadIdx.x;
    const int w = tid >> 6, lane = tid & 63;
    const int wy = w >> 1, wx = w & 1;
    const int quad = lane >> 4, mrow = lane & 15;

    long arow[4];
    #pragma unroll
    for (int j = 0; j < 4; ++j) {
        const int lr = (j * 256 + tid) >> 3;
        arow[j] = GATHER ? (long)prix[b * 3072 + tile * 128 + lr] : (long)lr;
    }

    floatx4 acc[4][4];
    #pragma unroll
    for (int i = 0; i < 4; i++)
        #pragma unroll
        for (int j = 0; j < 4; j++)
            acc[i][j] = floatx4{0.f, 0.f, 0.f, 0.f};

    const int nk = K >> 6;
    stage64(Ab, lda, arow, Bb, ldb, 0, tid, As[0], Bs[0]);
    for (int it = 0; it < nk; ++it) {
        const int cur = it & 1;
        __syncthreads();
        if (it + 1 < nk)
            stage64(Ab, lda, arow, Bb, ldb, (it + 1) << 6, tid, As[1 - cur], Bs[1 - cur]);
        compute64(As[cur], Bs[cur], wy, wx, quad, mrow, acc);
    }

    u16* Cb = C + rbase * ldc + (long)blockIdx.x * 128;
    const float* biasb = bias + (long)e * sBiasE + blockIdx.x * 128;
    #pragma unroll
    for (int ni = 0; ni < 4; ni++) {
        const int col = wx * 64 + ni * 16 + mrow;
        float bv = biasb[col];
        #pragma unroll
        for (int mi = 0; mi < 4; mi++) {
            #pragma unroll
            for (int r = 0; r < 4; r++) {
                const int row = wy * 64 + mi * 16 + quad * 4 + r;
                float v = acc[mi][ni][r] + bv;
                if (RELU) v = fmaxf(v, 0.f);
                Cb[(long)row * ldc + col] = f2bf_bits(v);
            }
        }
    }
}

// ---------------- LN1 on packed rows ----------------
__global__ __launch_bounds__(128)
void ln1_kernel(const float* __restrict__ x, const u16* __restrict__ tc,
                const int* __restrict__ prix, const int* __restrict__ act,
                const int* __restrict__ tmap, const int* __restrict__ pt,
                const float* __restrict__ s_all, const float* __restrict__ b_all,
                u16* __restrict__ hb) {
    int blk = blockIdx.x;
    int b = blk / 3072, pslot = blk % 3072;
    if (pslot >= pt[b]) return;
    long row = (long)b * 3072 + pslot;
    int tid = threadIdx.x, w = tid >> 6, lane = tid & 63;
    if (!act[row]) {
        *(ushort4*)(hb + row * 512 + tid * 4) = make_ushort4(0, 0, 0, 0);
        return;
    }
    int r = prix[row];
    int e = tmap[b * 32 + (pslot >> 7)];
    float4 xv = *(const float4*)(x + (long)r * 512 + tid * 4);
    ushort4 tu = *(const ushort4*)(tc + row * 512 + tid * 4);
    float v[4] = {xv.x + bf_bits2f(tu.x), xv.y + bf_bits2f(tu.y),
                  xv.z + bf_bits2f(tu.z), xv.w + bf_bits2f(tu.w)};
    float sum = v[0] + v[1] + v[2] + v[3];
    #pragma unroll
    for (int o = 32; o; o >>= 1) sum += __shfl_down(sum, o, 64);
    __shared__ float sh[4];
    if (lane == 0) sh[w] = sum;
    __syncthreads();
    float mu = (sh[0] + sh[1]) * (1.f / 512.f);
    float sq = 0.f;
    #pragma unroll
    for (int j = 0; j < 4; j++) { float d = v[j] - mu; sq += d * d; }
    #pragma unroll
    for (int o = 32; o; o >>= 1) sq += __shfl_down(sq, o, 64);
    if (lane == 0) sh[2 + w] = sq;
    __syncthreads();
    float inv = 1.f / sqrtf((sh[2] + sh[3]) * (1.f / 512.f) + 1e-5f);
    float4 sv = *(const float4*)(s_all + e * 512 + tid * 4);
    float4 bv = *(const float4*)(b_all + e * 512 + tid * 4);
    ushort4 ub;
    ub.x = f2bf_bits((v[0] - mu) * inv * sv.x + bv.x);
    ub.y = f2bf_bits((v[1] - mu) * inv * sv.y + bv.y);
    ub.z = f2bf_bits((v[2] - mu) * inv * sv.z + bv.z);
    ub.w = f2bf_bits((v[3] - mu) * inv * sv.w + bv.w);
    *(ushort4*)(hb + row * 512 + tid * 4) = ub;
}

// ---------------- LN2 + weighted accumulate over all 8 experts ----------------
__global__ __launch_bounds__(128)
void ln2acc_kernel(const u16* __restrict__ hb, const u16* __restrict__ t2,
                   const float* __restrict__ s_all, const float* __restrict__ b_all,
                   const float* __restrict__ rw, const int* __restrict__ smap,
                   float* __restrict__ out) {
    long r = blockIdx.x;
    int b = (int)(r >> 10);
    int tid = threadIdx.x, w = tid >> 6, lane = tid & 63;
    __shared__ float sh[4];
    float4 acc = make_float4(0.f, 0.f, 0.f, 0.f);
    for (int e = 0; e < 8; e++) {
        int ps = smap[r * 8 + e];
        if (ps >= 0) {   // block-uniform
            float wgt = rw[r * 8 + e];
            long row = (long)b * 3072 + ps;
            ushort4 hu = *(const ushort4*)(hb + row * 512 + tid * 4);
            ushort4 fu = *(const ushort4*)(t2 + row * 512 + tid * 4);
            float v[4] = {bf_bits2f(hu.x) + bf_bits2f(fu.x), bf_bits2f(hu.y) + bf_bits2f(fu.y),
                          bf_bits2f(hu.z) + bf_bits2f(fu.z), bf_bits2f(hu.w) + bf_bits2f(fu.w)};
            float sum = v[0] + v[1] + v[2] + v[3];
            #pragma unroll
            for (int o = 32; o; o >>= 1) sum += __shfl_down(sum, o, 64);
            if (lane == 0) sh[w] = sum;
            __syncthreads();
            float mu = (sh[0] + sh[1]) * (1.f / 512.f);
            float sq = 0.f;
            #pragma unroll
            for (int j = 0; j < 4; j++) { float d = v[j] - mu; sq += d * d; }
            #pragma unroll
            for (int o = 32; o; o >>= 1) sq += __shfl_down(sq, o, 64);
            if (lane == 0) sh[2 + w] = sq;
            __syncthreads();
            float inv = 1.f / sqrtf((sh[2] + sh[3]) * (1.f / 512.f) + 1e-5f);
            float4 sv = *(const float4*)(s_all + e * 512 + tid * 4);
            float4 bv = *(const float4*)(b_all + e * 512 + tid * 4);
            acc.x += wgt * ((v[0] - mu) * inv * sv.x + bv.x);
            acc.y += wgt * ((v[1] - mu) * inv * sv.y + bv.y);
            acc.z += wgt * ((v[2] - mu) * inv * sv.z + bv.z);
            acc.w += wgt * ((v[3] - mu) * inv * sv.w + bv.w);
            __syncthreads();
        }
    }
    *(float4*)(out + r * 512 + tid * 4) = acc;
}

// ---------------- workspace layout (bytes), ws_size = 256 MiB ----------------
static const size_t WB_B   = 0;           // 48 MiB: wq,wk,wv,wo (8x262144 each), w1 (8x1048576), w2 (8x1048576)
static const size_t RW_B   = 50331648;    // f32 [4096][8]
static const size_t PB_B   = 50462720;    // f32 [3][8][512]
static const size_t TT_B   = 50511872;    // i32[4] tiles per b
static const size_t PT_B   = 50511888;    // i32[4] packed rows per b
static const size_t TMAP_B = 50511904;    // i32 [4][32]
static const size_t PRIX_B = 50512416;    // i32 [4][3072]
static const size_t ACT_B  = 50561568;    // i32 [4][3072]
static const size_t SMAP_B = 50610720;    // i32 [4096][8]
static const size_t XB_B   = 50741792;    // bf16 [4096][512]
static const size_t Q8_B   = 54936096;    // bf16 packed Q [4][3072][512] (12.6 MiB)
static const size_t K8_B   = 88490528;    // bf16 [8][4096][512] (32 MiB)
static const size_t VT_B   = 122044960;   // bf16 [8][16][128][1024] (32 MiB)
static const size_t S_B    = 155599392;   // scratch region (FFN mid), 96 MiB
static const size_t OC_B   = Q8_B;        // fused attn out: block-exclusive alias of QP
static const size_t TC_B   = K8_B;        // bf16 [4][3072][512] — K dead after attn
static const size_t HB_B   = Q8_B;        // LN1 out — OC dead after Wo
static const size_t MID_B  = S_B;         // bf16 [4][3072][2048] (50 MB)
static const size_t T2_B   = VT_B;        // bf16 [4][3072][512] — VT dead after attn

extern "C" void kernel_launch(void* const* d_in, const int* in_sizes, int n_in,
                              void* d_out, int out_size, void* d_ws, size_t ws_size,
                              hipStream_t stream) {
    const float* x      = (const float*)d_in[0];
    const float* gate_w = (const float*)d_in[1];
    const float* gate_b = (const float*)d_in[2];
    const float* ln1_s  = (const float*)d_in[3];
    const float* ln1_b  = (const float*)d_in[4];
    const float* ln2_s  = (const float*)d_in[5];
    const float* ln2_b  = (const float*)d_in[6];
    const float* wq = (const float*)d_in[7];
    const float* wk = (const float*)d_in[8];
    const float* wv = (const float*)d_in[9];
    const float* wo = (const float*)d_in[10];
    const float* bo = (const float*)d_in[14];
    const float* w1 = (const float*)d_in[15];
    const float* b1 = (const float*)d_in[16];
    const float* w2 = (const float*)d_in[17];
    const float* b2 = (const float*)d_in[18];
    float* out = (float*)d_out;

    char* ws = (char*)d_ws;
    u16*   WB   = (u16*)(ws + WB_B);
    float* RW   = (float*)(ws + RW_B);
    float* PB   = (float*)(ws + PB_B);
    int*   TT   = (int*)(ws + TT_B);
    int*   PT   = (int*)(ws + PT_B);
    int*   TMAP = (int*)(ws + TMAP_B);
    int*   PRIX = (int*)(ws + PRIX_B);
    int*   ACT  = (int*)(ws + ACT_B);
    int*   SMAP = (int*)(ws + SMAP_B);
    u16*   XB   = (u16*)(ws + XB_B);
    u16*   QP   = (u16*)(ws + Q8_B);
    u16*   K8   = (u16*)(ws + K8_B);
    u16*   VT8  = (u16*)(ws + VT_B);
    u16*   OC   = (u16*)(ws + OC_B);
    u16*   TC   = (u16*)(ws + TC_B);
    u16*   HB   = (u16*)(ws + HB_B);
    u16*   MID  = (u16*)(ws + MID_B);
    u16*   T2   = (u16*)(ws + T2_B);

    // ---- setup ----
    cast_bf16_kernel<<<dim3(2096), 256, 0, stream>>>(x, XB, 4096 * 512 / 4,
                                                     (const float*)d_in[11], (const float*)d_in[12],
                                                     (const float*)d_in[13], PB);
    transpose_cast4_kernel<<<dim3(16,16,32), dim3(32,8), 0, stream>>>(wq, wk, wv, wo, WB);
    transpose_cast_kernel<<<dim3(64,16,8), dim3(32,8), 0, stream>>>(w1, WB + 8388608,  512,  2048, 1048576, 1048576);
    transpose_cast_kernel<<<dim3(16,64,8), dim3(32,8), 0, stream>>>(w2, WB + 16777216, 2048, 512,  1048576, 1048576);
    router_kernel<<<4096, 512, 0, stream>>>(x, gate_w, gate_b, RW, out + 2097152);
    build_lists_kernel<<<4, 256, 0, stream>>>(RW, PRIX, ACT, SMAP, TMAP, TT, PT);

    const float isq = 0.08838834764831845f;  // 1/sqrt(128)

    // ---- K + V for all 8 experts in one launch (z<8: K normal, z>=8: V transposed) ----
    gemm_kv_kernel<<<dim3(4,32,16), 256, 0, stream>>>(XB, WB + 2097152, K8, VT8, PB + 4096);
    // ---- Q only for packed (routed) rows, gathered from x ----
    gemm_packed_kernel<false, true><<<dim3(4,96), 256, 0, stream>>>(
        XB, 512, WB, 512, 262144, QP, 512, PB, 512, TMAP, TT, 512, PRIX);

    // ---- fused attention (R2-proven structure, 8 x 128-key steps) ----
    attn_fused_kernel<<<dim3(24, 16), 256, 0, stream>>>(QP, K8, VT8, OC, TMAP, TT, isq);

    // ---- Wo ----
    gemm_packed_kernel<false, false><<<dim3(4,96), 256, 0, stream>>>(
        OC, 512, WB + 6291456, 512, 262144, TC, 512, bo, 512, TMAP, TT, 512, nullptr);
    // ---- LN1 ----
    ln1_kernel<<<12288, 128, 0, stream>>>(x, TC, PRIX, ACT, TMAP, PT, ln1_s, ln1_b, HB);
    // ---- FFN1 ----
    gemm_packed_kernel<true, false><<<dim3(16,96), 256, 0, stream>>>(
        HB, 512, WB + 8388608, 512, 1048576, MID, 2048, b1, 2048, TMAP, TT, 512, nullptr);
    // ---- FFN2 ----
    gemm_packed_kernel<false, false><<<dim3(4,96), 256, 0, stream>>>(
        MID, 2048, WB + 16777216, 2048, 1048576, T2, 512, b2, 512, TMAP, TT, 2048, nullptr);
    // ---- LN2 + routing-weighted accumulate ----
    ln2acc_kernel<<<4096, 128, 0, stream>>>(HB, T2, ln2_s, ln2_b, RW, SMAP, out);
}